// Round 1
// baseline (9456.503 us; speedup 1.0000x reference)
//
#include <hip/hip_runtime.h>
#include <cstdint>
#include <cstddef>

// BinaryTreeLSTM fp32 baseline.
// Level structure:
//   leaves: fioux = x @ w_fioux.T (+b, only f-col bias is nonzero and f unused)
//           c = sig(ix)*tanh(ux); h = sig(ox)*tanh(c)
//   internal (x = 0): gates = child_h @ [w_iouh; w_fh].T  (child_h = h_prev
//           reinterpreted [B*n, 2048] -- contiguous, no gather)
//           i=sig(ih+b_i) o=sig(oh+b_o) u=tanh(uh+b_u)
//           f_l=sig(b_f+fh_l) f_r=sig(b_f+fh_r)
//           c = i*u + f_l*c_l + f_r*c_r ; h = o*tanh(c)

#define MEMD 1024
#define CHUNK 2048   // rows per GEMM+gate chunk (bounds gates scratch)

__device__ __forceinline__ float sig_(float x) { return 1.0f / (1.0f + __expf(-x)); }

// C[r, col0+c] = sum_k A[r,k] * W[c,k]   (A: [M,K] row-major, W: [N,K] row-major)
__global__ __launch_bounds__(256)
void gemm_atb(const float* __restrict__ A, const float* __restrict__ W,
              float* __restrict__ C, int M, int N, int K, int ldc, int col0)
{
    __shared__ float As[16][68];
    __shared__ float Ws[16][68];
    const int tid  = threadIdx.x;
    const int row0 = blockIdx.y * 64;
    const int colb = blockIdx.x * 64;
    const int lrow = tid >> 2;           // 0..63
    const int lk   = (tid & 3) << 2;     // 0,4,8,12
    const int tx4  = (tid & 15) << 2;    // col group
    const int ty4  = (tid >> 4) << 2;    // row group
    const int arow = min(row0 + lrow, M - 1);   // clamp for ragged last tile
    const float* Ap = A + (size_t)arow * K + lk;
    const float* Wp = W + (size_t)(colb + lrow) * K + lk;

    float acc[4][4] = {};
    for (int k0 = 0; k0 < K; k0 += 16) {
        const float4 av = *(const float4*)(Ap + k0);
        const float4 wv = *(const float4*)(Wp + k0);
        __syncthreads();
        As[lk+0][lrow] = av.x; As[lk+1][lrow] = av.y;
        As[lk+2][lrow] = av.z; As[lk+3][lrow] = av.w;
        Ws[lk+0][lrow] = wv.x; Ws[lk+1][lrow] = wv.y;
        Ws[lk+2][lrow] = wv.z; Ws[lk+3][lrow] = wv.w;
        __syncthreads();
        #pragma unroll
        for (int k = 0; k < 16; ++k) {
            const float a0 = As[k][ty4+0], a1 = As[k][ty4+1],
                        a2 = As[k][ty4+2], a3 = As[k][ty4+3];
            const float b0 = Ws[k][tx4+0], b1 = Ws[k][tx4+1],
                        b2 = Ws[k][tx4+2], b3 = Ws[k][tx4+3];
            acc[0][0] += a0*b0; acc[0][1] += a0*b1; acc[0][2] += a0*b2; acc[0][3] += a0*b3;
            acc[1][0] += a1*b0; acc[1][1] += a1*b1; acc[1][2] += a1*b2; acc[1][3] += a1*b3;
            acc[2][0] += a2*b0; acc[2][1] += a2*b1; acc[2][2] += a2*b2; acc[2][3] += a2*b3;
            acc[3][0] += a3*b0; acc[3][1] += a3*b1; acc[3][2] += a3*b2; acc[3][3] += a3*b3;
        }
    }
    #pragma unroll
    for (int i = 0; i < 4; ++i) {
        const int r = row0 + ty4 + i;
        if (r < M) {
            float* cp = C + (size_t)r * ldc + col0 + colb + tx4;
            cp[0] = acc[i][0]; cp[1] = acc[i][1]; cp[2] = acc[i][2]; cp[3] = acc[i][3];
        }
    }
}

// g: [rows, 4096] pre-activations (x@w_fioux.T, no bias). Layout: fx|ix|ox|ux
__global__ void leaf_gates(const float* __restrict__ g, const float* __restrict__ b,
                           float* __restrict__ c_out, float* __restrict__ h_out, int rows)
{
    const int idx = blockIdx.x * blockDim.x + threadIdx.x;
    if (idx >= rows * MEMD) return;
    const int r = idx >> 10, j = idx & 1023;
    const float* gr = g + (size_t)r * 4096;
    const float ix = gr[1024 + j] + b[1024 + j];
    const float ox = gr[2048 + j] + b[2048 + j];
    const float ux = gr[3072 + j] + b[3072 + j];
    const float c  = sig_(ix) * tanhf(ux);
    c_out[idx] = c;
    h_out[idx] = sig_(ox) * tanhf(c);
}

// g: [rows, 5120] = [ih|oh|uh|fh_l|fh_r]; c_prev viewed [rows, 2048]
__global__ void node_gates(const float* __restrict__ g, const float* __restrict__ b,
                           const float* __restrict__ c_prev,
                           float* __restrict__ c_out, float* __restrict__ h_out, int rows)
{
    const int idx = blockIdx.x * blockDim.x + threadIdx.x;
    if (idx >= rows * MEMD) return;
    const int r = idx >> 10, j = idx & 1023;
    const float* gr = g + (size_t)r * 5120;
    const float ih = gr[j]         + b[1024 + j];
    const float oh = gr[1024 + j]  + b[2048 + j];
    const float uh = gr[2048 + j]  + b[3072 + j];
    const float fl = gr[3072 + j]  + b[j];
    const float fr = gr[4096 + j]  + b[j];
    const float cl = c_prev[(size_t)r * 2048 + j];
    const float cr = c_prev[(size_t)r * 2048 + 1024 + j];
    const float i = sig_(ih), o = sig_(oh), u = tanhf(uh);
    const float c = i * u + sig_(fl) * cl + sig_(fr) * cr;
    c_out[idx] = c;
    h_out[idx] = o * tanhf(c);
}

extern "C" void kernel_launch(void* const* d_in, const int* in_sizes, int n_in,
                              void* d_out, int out_size, void* d_ws, size_t ws_size,
                              hipStream_t stream)
{
    const float* inputs  = (const float*)d_in[0];  // [32, 512, 1024]
    const float* w_fioux = (const float*)d_in[1];  // [4096, 1024]
    const float* b_fioux = (const float*)d_in[2];  // [4096]
    const float* w_iouh  = (const float*)d_in[3];  // [3072, 2048]
    const float* w_fh    = (const float*)d_in[4];  // [2048, 2048]
    float* out = (float*)d_out;                    // [32, 1024]
    float* ws  = (float*)d_ws;

    // ws layout (f32 elements):
    //   h_a: 16384*1024      c_a: 16384*1024
    //   h_b:  8192*1024      c_b:  8192*1024
    //   gbuf: CHUNK*5120
    float* h_a  = ws;
    float* c_a  = h_a + (size_t)16384 * 1024;
    float* h_b  = c_a + (size_t)16384 * 1024;
    float* c_b  = h_b + (size_t)8192 * 1024;
    float* gbuf = c_b + (size_t)8192 * 1024;
    // total: (2*16384 + 2*8192 + CHUNK*5) * 1024 * 4 B  =  232 MiB

    // ---- Leaf level: 16384 rows, K=1024, N=4096 ----
    for (int r0 = 0; r0 < 16384; r0 += CHUNK) {
        const float* A = inputs + (size_t)r0 * 1024;
        dim3 grid(4096 / 64, CHUNK / 64);
        gemm_atb<<<grid, 256, 0, stream>>>(A, w_fioux, gbuf, CHUNK, 4096, 1024, 4096, 0);
        leaf_gates<<<(CHUNK * MEMD) / 256, 256, 0, stream>>>(
            gbuf, b_fioux, c_a + (size_t)r0 * 1024, h_a + (size_t)r0 * 1024, CHUNK);
    }

    // ---- Internal levels: n = 256 ... 1 ----
    float *hp = h_a, *cp = c_a, *hn = h_b, *cn = c_b;
    for (int n = 256; n >= 1; n >>= 1) {
        const int rows = 32 * n;
        float* h_dst = (n == 1) ? out : hn;
        for (int r0 = 0; r0 < rows; r0 += CHUNK) {
            const int m = (rows - r0 < CHUNK) ? (rows - r0) : CHUNK;
            const float* A = hp + (size_t)r0 * 2048;   // child_h view [m, 2048]
            dim3 g1(3072 / 64, (m + 63) / 64);
            dim3 g2(2048 / 64, (m + 63) / 64);
            gemm_atb<<<g1, 256, 0, stream>>>(A, w_iouh, gbuf, m, 3072, 2048, 5120, 0);
            gemm_atb<<<g2, 256, 0, stream>>>(A, w_fh,   gbuf, m, 2048, 2048, 5120, 3072);
            const int total = m * MEMD;
            node_gates<<<(total + 255) / 256, 256, 0, stream>>>(
                gbuf, b_fioux, cp + (size_t)r0 * 2048,
                cn + (size_t)r0 * 1024, h_dst + (size_t)r0 * 1024, m);
        }
        float* t;
        t = hp; hp = hn; hn = t;
        t = cp; cp = cn; cn = t;
    }
    (void)in_sizes; (void)n_in; (void)out_size; (void)ws_size;
}

// Round 2
// 1190.429 us; speedup vs baseline: 7.9438x; 7.9438x over previous
//
#include <hip/hip_runtime.h>
#include <cstdint>
#include <cstddef>

// BinaryTreeLSTM — bf16 MFMA GEMM + fp32 gates.
// Leaf:     [i|o|u] = x_bf @ wfx_bf.T          (N=3072; f-gate dead at leaves)
//           c = sig(ix)*tanh(ux); h = sig(ox)*tanh(c)
// Internal: [ih|oh|uh|fl|fr] = h_prev(bf16,[m,2048]) @ wcat_bf.T  (N=5120)
//           c = i*u + sig(fl+bf)*c_l + sig(fr+bf)*c_r; h = o*tanh(c)
// h kept bf16 (feeds next GEMM); c kept fp32 (recurrence accuracy).

#define BM 128
#define BN 128
#define BK 32

typedef __attribute__((ext_vector_type(8))) short bf16x8;
typedef __attribute__((ext_vector_type(4))) float f32x4;

__device__ __forceinline__ float sig_(float x) { return 1.0f / (1.0f + __expf(-x)); }

__device__ __forceinline__ unsigned short f2bf_(float x) {
    union { float f; uint32_t u; } v; v.f = x;
    uint32_t r = v.u + 0x7fffu + ((v.u >> 16) & 1u);   // RNE
    return (unsigned short)(r >> 16);
}

#define SWZ(r) (((r) & 3) ^ (((r) >> 2) & 3))

#define GL16(g, l) __builtin_amdgcn_global_load_lds( \
    (const __attribute__((address_space(1))) void*)(g), \
    (__attribute__((address_space(3))) void*)(l), 16, 0, 0)

// C[M,N] fp32 = A[M,K]bf16 @ W[N,K]bf16^T. K%32==0, N%128==0. ldc=N.
__global__ __launch_bounds__(256)
void gemm_bf16(const unsigned short* __restrict__ A,
               const unsigned short* __restrict__ W,
               float* __restrict__ C, int M, int N, int K)
{
    __shared__ unsigned short lA[BM * BK];   // 8 KB, rows of 64 B (4 slots x 16 B)
    __shared__ unsigned short lB[BN * BK];   // 8 KB

    const int tid = threadIdx.x;
    const int wv  = tid >> 6;           // wave 0..3
    const int ln  = tid & 63;
    const int wr  = wv >> 1;            // wave row (0/1) -> 64 rows
    const int wc  = wv & 1;             // wave col (0/1) -> 64 cols
    const int row0 = blockIdx.y * BM;
    const int colb = blockIdx.x * BN;

    // ---- staging source addresses (pre-swizzled global, linear LDS dest) ----
    // chunk c covers LDS bytes [c*4096 + wv*1024, +1024); lane ln -> +ln*16
    const unsigned short* srcA[2];
    const unsigned short* srcB[2];
    int ldsOff[2];
    #pragma unroll
    for (int c = 0; c < 2; ++c) {
        const int Lb  = c * 4096 + wv * 1024 + ln * 16;
        const int row = Lb >> 6;
        const int sl  = ((Lb >> 4) & 3) ^ SWZ(row);
        const int ar  = min(row0 + row, M - 1);
        srcA[c] = A + (size_t)ar * K + sl * 8;
        srcB[c] = W + (size_t)(colb + row) * K + sl * 8;
        ldsOff[c] = c * 2048 + wv * 512;   // ushort elems, wave-uniform
    }

    // ---- fragment LDS offsets (k0-independent) ----
    int aoff[4], boff[4];
    #pragma unroll
    for (int i = 0; i < 4; ++i) {
        const int arow = wr * 64 + i * 16 + (ln & 15);
        const int brow = wc * 64 + i * 16 + (ln & 15);
        const int g    = ln >> 4;
        aoff[i] = arow * 32 + (g ^ SWZ(arow)) * 8;
        boff[i] = brow * 32 + (g ^ SWZ(brow)) * 8;
    }

    f32x4 acc[4][4] = {};

    for (int k0 = 0; k0 < K; k0 += BK) {
        __syncthreads();
        GL16(srcA[0] + k0, lA + ldsOff[0]);
        GL16(srcA[1] + k0, lA + ldsOff[1]);
        GL16(srcB[0] + k0, lB + ldsOff[0]);
        GL16(srcB[1] + k0, lB + ldsOff[1]);
        __syncthreads();

        bf16x8 af[4], bf[4];
        #pragma unroll
        for (int i = 0; i < 4; ++i) {
            af[i] = *(const bf16x8*)(lA + aoff[i]);
            bf[i] = *(const bf16x8*)(lB + boff[i]);
        }
        #pragma unroll
        for (int mi = 0; mi < 4; ++mi)
            #pragma unroll
            for (int ni = 0; ni < 4; ++ni)
                acc[mi][ni] = __builtin_amdgcn_mfma_f32_16x16x32_bf16(
                    af[mi], bf[ni], acc[mi][ni], 0, 0, 0);
    }

    // C/D map: col = lane&15, row = (lane>>4)*4 + reg   [measured m89/m91]
    #pragma unroll
    for (int mi = 0; mi < 4; ++mi) {
        #pragma unroll
        for (int ni = 0; ni < 4; ++ni) {
            const int col = colb + wc * 64 + ni * 16 + (ln & 15);
            #pragma unroll
            for (int reg = 0; reg < 4; ++reg) {
                const int r = row0 + wr * 64 + mi * 16 + (ln >> 4) * 4 + reg;
                if (r < M) C[(size_t)r * N + col] = acc[mi][ni][reg];
            }
        }
    }
}

// fp32 -> bf16 (RNE), 4 elems/thread
__global__ void f2bf_vec(const float* __restrict__ src, unsigned short* __restrict__ dst, int n4)
{
    const int i = blockIdx.x * blockDim.x + threadIdx.x;
    if (i >= n4) return;
    const float4 v = ((const float4*)src)[i];
    ushort4 o;
    o.x = f2bf_(v.x); o.y = f2bf_(v.y); o.z = f2bf_(v.z); o.w = f2bf_(v.w);
    ((ushort4*)dst)[i] = o;
}

// g: [rows,3072] = [ix|ox|ux]
__global__ void leaf_gates(const float* __restrict__ g, const float* __restrict__ b,
                           float* __restrict__ c_out, unsigned short* __restrict__ h_out,
                           int rows)
{
    const int idx = blockIdx.x * blockDim.x + threadIdx.x;
    if (idx >= rows * 256) return;
    const int r = idx >> 8, q = (idx & 255) << 2;
    const float* gr = g + (size_t)r * 3072;
    const float4 ix = *(const float4*)(gr + q);
    const float4 ox = *(const float4*)(gr + 1024 + q);
    const float4 ux = *(const float4*)(gr + 2048 + q);
    const float4 bi = *(const float4*)(b + 1024 + q);
    const float4 bo = *(const float4*)(b + 2048 + q);
    const float4 bu = *(const float4*)(b + 3072 + q);
    float4 co; ushort4 ho;
    {
        const float c0 = sig_(ix.x + bi.x) * tanhf(ux.x + bu.x);
        const float c1 = sig_(ix.y + bi.y) * tanhf(ux.y + bu.y);
        const float c2 = sig_(ix.z + bi.z) * tanhf(ux.z + bu.z);
        const float c3 = sig_(ix.w + bi.w) * tanhf(ux.w + bu.w);
        co.x = c0; co.y = c1; co.z = c2; co.w = c3;
        ho.x = f2bf_(sig_(ox.x + bo.x) * tanhf(c0));
        ho.y = f2bf_(sig_(ox.y + bo.y) * tanhf(c1));
        ho.z = f2bf_(sig_(ox.z + bo.z) * tanhf(c2));
        ho.w = f2bf_(sig_(ox.w + bo.w) * tanhf(c3));
    }
    *(float4*)(c_out + (size_t)r * 1024 + q) = co;
    *(ushort4*)(h_out + (size_t)r * 1024 + q) = ho;
}

// g: [rows,5120] = [ih|oh|uh|fl|fr]; c_prev viewed [rows,2048]
__global__ void node_gates(const float* __restrict__ g, const float* __restrict__ b,
                           const float* __restrict__ c_prev,
                           float* __restrict__ c_out, unsigned short* __restrict__ h_bf,
                           float* __restrict__ h_f32, int rows)
{
    const int idx = blockIdx.x * blockDim.x + threadIdx.x;
    if (idx >= rows * 256) return;
    const int r = idx >> 8, q = (idx & 255) << 2;
    const float* gr = g + (size_t)r * 5120;
    const float4 ih = *(const float4*)(gr + q);
    const float4 oh = *(const float4*)(gr + 1024 + q);
    const float4 uh = *(const float4*)(gr + 2048 + q);
    const float4 fl = *(const float4*)(gr + 3072 + q);
    const float4 fr = *(const float4*)(gr + 4096 + q);
    const float4 bi = *(const float4*)(b + 1024 + q);
    const float4 bo = *(const float4*)(b + 2048 + q);
    const float4 bu = *(const float4*)(b + 3072 + q);
    const float4 bff = *(const float4*)(b + q);
    const float4 cl = *(const float4*)(c_prev + (size_t)r * 2048 + q);
    const float4 cr = *(const float4*)(c_prev + (size_t)r * 2048 + 1024 + q);

    float4 co, hv;
    {
        const float c0 = sig_(ih.x + bi.x) * tanhf(uh.x + bu.x) + sig_(fl.x + bff.x) * cl.x + sig_(fr.x + bff.x) * cr.x;
        const float c1 = sig_(ih.y + bi.y) * tanhf(uh.y + bu.y) + sig_(fl.y + bff.y) * cl.y + sig_(fr.y + bff.y) * cr.y;
        const float c2 = sig_(ih.z + bi.z) * tanhf(uh.z + bu.z) + sig_(fl.z + bff.z) * cl.z + sig_(fr.z + bff.z) * cr.z;
        const float c3 = sig_(ih.w + bi.w) * tanhf(uh.w + bu.w) + sig_(fl.w + bff.w) * cl.w + sig_(fr.w + bff.w) * cr.w;
        co.x = c0; co.y = c1; co.z = c2; co.w = c3;
        hv.x = sig_(oh.x + bo.x) * tanhf(c0);
        hv.y = sig_(oh.y + bo.y) * tanhf(c1);
        hv.z = sig_(oh.z + bo.z) * tanhf(c2);
        hv.w = sig_(oh.w + bo.w) * tanhf(c3);
    }
    *(float4*)(c_out + (size_t)r * 1024 + q) = co;
    ushort4 ho;
    ho.x = f2bf_(hv.x); ho.y = f2bf_(hv.y); ho.z = f2bf_(hv.z); ho.w = f2bf_(hv.w);
    *(ushort4*)(h_bf + (size_t)r * 1024 + q) = ho;
    if (h_f32) *(float4*)(h_f32 + (size_t)r * 1024 + q) = hv;
}

extern "C" void kernel_launch(void* const* d_in, const int* in_sizes, int n_in,
                              void* d_out, int out_size, void* d_ws, size_t ws_size,
                              hipStream_t stream)
{
    const float* inputs  = (const float*)d_in[0];  // [32,512,1024] = [16384,1024]
    const float* w_fioux = (const float*)d_in[1];  // [4096,1024]
    const float* b_fioux = (const float*)d_in[2];  // [4096]
    const float* w_iouh  = (const float*)d_in[3];  // [3072,2048]
    const float* w_fh    = (const float*)d_in[4];  // [2048,2048]
    float* out = (float*)d_out;                    // [32,1024]

    // ---- ws layout (220.2 MB total) ----
    float* ws = (float*)d_ws;
    float*          c_a  = ws;                                    // 16384*1024 f32 (67.1 MB)
    float*          c_b  = c_a + (size_t)16384 * 1024;            //  8192*1024 f32 (33.6 MB)
    unsigned short* h_a  = (unsigned short*)(c_b + (size_t)8192 * 1024); // 16384*1024 bf16 (33.6)
    unsigned short* h_b  = h_a + (size_t)16384 * 1024;            //  8192*1024 bf16 (16.8)
    unsigned short* wfx  = h_b + (size_t)8192 * 1024;             //  3072*1024 bf16 (6.3)
    unsigned short* wcat = wfx + (size_t)3072 * 1024;             //  5120*2048 bf16 (21.0)
    float*          gbuf = (float*)(wcat + (size_t)5120 * 2048);  //  2048*5120 f32 (41.9)
    // x_bf aliases c_b (c_b first written only at level n=256, after leaf GEMMs)
    unsigned short* x_bf = (unsigned short*)c_b;                  // 16384*1024 bf16

    // ---- one-time fp32 -> bf16 conversions ----
    f2bf_vec<<<(16384 * 256) / 256, 256, 0, stream>>>(inputs, x_bf, 16384 * 256);
    f2bf_vec<<<(3072 * 256) / 256, 256, 0, stream>>>(w_fioux + (size_t)1024 * 1024, wfx, 3072 * 256);
    f2bf_vec<<<(3072 * 512) / 256, 256, 0, stream>>>(w_iouh, wcat, 3072 * 512);
    f2bf_vec<<<(2048 * 512) / 256, 256, 0, stream>>>(w_fh, wcat + (size_t)3072 * 2048, 2048 * 512);

    // ---- leaf level: 16384 rows, K=1024, N=3072 ----
    for (int r0 = 0; r0 < 16384; r0 += 2048) {
        gemm_bf16<<<dim3(3072 / BN, 2048 / BM), 256, 0, stream>>>(
            x_bf + (size_t)r0 * 1024, wfx, gbuf, 2048, 3072, 1024);
        leaf_gates<<<(2048 * 256) / 256, 256, 0, stream>>>(
            gbuf, b_fioux, c_a + (size_t)r0 * 1024, h_a + (size_t)r0 * 1024, 2048);
    }

    // ---- internal levels: n = 256 .. 1 ----
    unsigned short *hp = h_a, *hn = h_b;
    float *cp = c_a, *cn = c_b;
    for (int n = 256; n >= 1; n >>= 1) {
        const int rows = 32 * n;
        for (int r0 = 0; r0 < rows; r0 += 2048) {
            const int m = (rows - r0 < 2048) ? (rows - r0) : 2048;
            gemm_bf16<<<dim3(5120 / BN, (m + BM - 1) / BM), 256, 0, stream>>>(
                hp + (size_t)r0 * 2048, wcat, gbuf, m, 5120, 2048);
            node_gates<<<(m * 256 + 255) / 256, 256, 0, stream>>>(
                gbuf, b_fioux, cp + (size_t)r0 * 2048,
                cn + (size_t)r0 * 1024, hn + (size_t)r0 * 1024,
                (n == 1) ? out : nullptr, m);
        }
        unsigned short* th = hp; hp = hn; hn = th;
        float* tc = cp; cp = cn; cn = tc;
    }
    (void)in_sizes; (void)n_in; (void)out_size; (void)ws_size;
}

// Round 3
// 923.452 us; speedup vs baseline: 10.2404x; 1.2891x over previous
//
#include <hip/hip_runtime.h>
#include <cstdint>
#include <cstddef>

// BinaryTreeLSTM — 256^2 8-wave pipelined bf16 MFMA GEMM + fp32 gates.
// Leaf:     [i|o|u] = x_bf @ wfx_bf.T          (N=3072; f-gate dead at leaves)
// Internal: [ih|oh|uh|fl|fr] = h_prev(bf16,[m,2048]) @ wcat_bf.T  (N=5120)
// h kept bf16 (feeds next GEMM); c kept fp32; pre-activations (gbuf) bf16.

typedef __attribute__((ext_vector_type(8))) short bf16x8;
typedef __attribute__((ext_vector_type(4))) float f32x4;

__device__ __forceinline__ float sig_(float x) { return 1.0f / (1.0f + __expf(-x)); }

__device__ __forceinline__ unsigned short f2bf_(float x) {
    union { float f; uint32_t u; } v; v.f = x;
    uint32_t r = v.u + 0x7fffu + ((v.u >> 16) & 1u);   // RNE
    return (unsigned short)(r >> 16);
}
__device__ __forceinline__ float bf2f_(unsigned short u) {
    union { uint32_t u; float f; } v; v.u = ((uint32_t)u) << 16; return v.f;
}

#define GL16(g, l) __builtin_amdgcn_global_load_lds( \
    (const __attribute__((address_space(1))) void*)(g), \
    (__attribute__((address_space(3))) void*)(l), 16, 0, 0)

// ---------------------------------------------------------------------------
// gemm256: C[M,N] bf16 = A[M,K]bf16 @ W[N,K]bf16^T.
// M,N multiples of 256; K multiple of 64, K/64 >= 4.
// 512 threads = 8 waves (2 Mx4 N), wave output 128x64, acc 8x4 f32x4.
// LDS: per operand 4 circular k-half slots of [256 rows][32 k] bf16 (16 KB),
// slot addr: row*64B + ((g ^ ((row>>1)&3))*16B  -> 2-way-max bank aliasing.
// Pipeline: phase f reads slot f&3; issues k-half f+3; end-of-phase
// s_waitcnt vmcnt(8) (counted, never 0 mid-loop) + raw s_barrier.
// ---------------------------------------------------------------------------
__global__ __launch_bounds__(512, 2)
void gemm256(const unsigned short* __restrict__ A,
             const unsigned short* __restrict__ W,
             unsigned short* __restrict__ C, int M, int N, int K)
{
    __shared__ unsigned short lA[4 * 8192];   // 64 KB
    __shared__ unsigned short lB[4 * 8192];   // 64 KB

    const int tid = threadIdx.x;
    const int ln  = tid & 63;
    const int wv  = tid >> 6;        // 0..7
    const int wrp = wv >> 2;         // 0..1 : output rows wrp*128..+127
    const int wcp = wv & 3;          // 0..3 : output cols wcp*64..+63
    const int row0 = blockIdx.y * 256;
    const int colb = blockIdx.x * 256;

    // staging: thread covers slot bytes tid*16 and 8192+tid*16
    const int rowS = tid >> 2;                        // 0..127 (load1: +128)
    const int gS   = (tid & 3) ^ ((tid >> 3) & 3);    // same for both loads
    const unsigned short* a0 = A + (size_t)min(row0 + rowS,       M - 1) * K + gS * 8;
    const unsigned short* a1 = A + (size_t)min(row0 + rowS + 128, M - 1) * K + gS * 8;
    const unsigned short* b0 = W + (size_t)(colb + rowS)       * K + gS * 8;
    const unsigned short* b1 = W + (size_t)(colb + rowS + 128) * K + gS * 8;
    const int ld0 = tid * 8;          // ushort offset within slot
    const int ld1 = tid * 8 + 4096;

    // fragment read offsets (ushort units, slot-relative)
    int offA[8], offB[4];
    #pragma unroll
    for (int i = 0; i < 8; ++i) {
        const int r = wrp * 128 + i * 16 + (ln & 15);
        offA[i] = r * 32 + ((ln >> 4) ^ ((r >> 1) & 3)) * 8;
    }
    #pragma unroll
    for (int i = 0; i < 4; ++i) {
        const int r = wcp * 64 + i * 16 + (ln & 15);
        offB[i] = r * 32 + ((ln >> 4) ^ ((r >> 1) & 3)) * 8;
    }

    f32x4 acc[8][4] = {};
    const int NT = K >> 6;

#define ISSUE_KH(kh) do { \
    const int _sl = (kh) & 3; \
    const size_t _ko = (size_t)(kh) * 32; \
    GL16(a0 + _ko, lA + _sl * 8192 + ld0); \
    GL16(a1 + _ko, lA + _sl * 8192 + ld1); \
    GL16(b0 + _ko, lB + _sl * 8192 + ld0); \
    GL16(b1 + _ko, lB + _sl * 8192 + ld1); \
} while (0)

#define PHASE(SLOT, KH, DOISS, WAITN, DOBAR) do { \
    const unsigned short* _pa = lA + (SLOT) * 8192; \
    const unsigned short* _pb = lB + (SLOT) * 8192; \
    bf16x8 _af[8], _bf[4]; \
    _Pragma("unroll") for (int _i = 0; _i < 8; ++_i) _af[_i] = *(const bf16x8*)(_pa + offA[_i]); \
    _Pragma("unroll") for (int _i = 0; _i < 4; ++_i) _bf[_i] = *(const bf16x8*)(_pb + offB[_i]); \
    if (DOISS) ISSUE_KH(KH); \
    __builtin_amdgcn_s_setprio(1); \
    _Pragma("unroll") for (int _m = 0; _m < 8; ++_m) \
        _Pragma("unroll") for (int _n = 0; _n < 4; ++_n) \
            acc[_m][_n] = __builtin_amdgcn_mfma_f32_16x16x32_bf16(_af[_m], _bf[_n], acc[_m][_n], 0, 0, 0); \
    __builtin_amdgcn_s_setprio(0); \
    if ((WAITN) == 8)      asm volatile("s_waitcnt vmcnt(8)" ::: "memory"); \
    else if ((WAITN) == 4) asm volatile("s_waitcnt vmcnt(4)" ::: "memory"); \
    else if ((WAITN) == 0) asm volatile("s_waitcnt vmcnt(0)" ::: "memory"); \
    if (DOBAR) asm volatile("s_barrier" ::: "memory"); \
} while (0)

    // prologue: stage k-halves 0,1,2 ; ensure k-half 0 landed (keep 8 in flight)
    ISSUE_KH(0); ISSUE_KH(1); ISSUE_KH(2);
    asm volatile("s_waitcnt vmcnt(8)" ::: "memory");
    asm volatile("s_barrier" ::: "memory");

    for (int t = 0; t <= NT - 3; ++t) {
        const int ph = 2 * t;
        PHASE((ph) & 3,     ph + 3, 1, 8, 1);
        PHASE((ph + 1) & 3, ph + 4, 1, 8, 1);
    }
    {
        const int ph = 2 * NT - 4;
        PHASE((ph) & 3,     ph + 3, 1,  8, 1);   // issues last k-half 2NT-1
        PHASE((ph + 1) & 3, 0,      0,  4, 1);
        PHASE((ph + 2) & 3, 0,      0,  0, 1);
        PHASE((ph + 3) & 3, 0,      0, -1, 0);
    }
#undef PHASE
#undef ISSUE_KH

    // epilogue: C/D map col=lane&15, row=(lane>>4)*4+reg  [m89/m91]
    #pragma unroll
    for (int mi = 0; mi < 8; ++mi) {
        #pragma unroll
        for (int ni = 0; ni < 4; ++ni) {
            const int col = colb + wcp * 64 + ni * 16 + (ln & 15);
            #pragma unroll
            for (int rg = 0; rg < 4; ++rg) {
                const int r = row0 + wrp * 128 + mi * 16 + (ln >> 4) * 4 + rg;
                if (r < M) C[(size_t)r * N + col] = f2bf_(acc[mi][ni][rg]);
            }
        }
    }
}

// ---------------------------------------------------------------------------
// gemm128: round-2 validated 128^2 kernel (bf16 output) — tail levels (M<=1024)
// ---------------------------------------------------------------------------
#define SWZ(r) (((r) & 3) ^ (((r) >> 2) & 3))

__global__ __launch_bounds__(256)
void gemm128(const unsigned short* __restrict__ A,
             const unsigned short* __restrict__ W,
             unsigned short* __restrict__ C, int M, int N, int K)
{
    __shared__ unsigned short lA[128 * 32];
    __shared__ unsigned short lB[128 * 32];

    const int tid = threadIdx.x;
    const int wv  = tid >> 6;
    const int ln  = tid & 63;
    const int wr  = wv >> 1;
    const int wc  = wv & 1;
    const int row0 = blockIdx.y * 128;
    const int colb = blockIdx.x * 128;

    const unsigned short* srcA[2];
    const unsigned short* srcB[2];
    int ldsOff[2];
    #pragma unroll
    for (int c = 0; c < 2; ++c) {
        const int Lb  = c * 4096 + wv * 1024 + ln * 16;
        const int row = Lb >> 6;
        const int sl  = ((Lb >> 4) & 3) ^ SWZ(row);
        const int ar  = min(row0 + row, M - 1);
        srcA[c] = A + (size_t)ar * K + sl * 8;
        srcB[c] = W + (size_t)(colb + row) * K + sl * 8;
        ldsOff[c] = c * 2048 + wv * 512;
    }

    int aoff[4], boff[4];
    #pragma unroll
    for (int i = 0; i < 4; ++i) {
        const int arow = wr * 64 + i * 16 + (ln & 15);
        const int brow = wc * 64 + i * 16 + (ln & 15);
        const int g    = ln >> 4;
        aoff[i] = arow * 32 + (g ^ SWZ(arow)) * 8;
        boff[i] = brow * 32 + (g ^ SWZ(brow)) * 8;
    }

    f32x4 acc[4][4] = {};

    for (int k0 = 0; k0 < K; k0 += 32) {
        __syncthreads();
        GL16(srcA[0] + k0, lA + ldsOff[0]);
        GL16(srcA[1] + k0, lA + ldsOff[1]);
        GL16(srcB[0] + k0, lB + ldsOff[0]);
        GL16(srcB[1] + k0, lB + ldsOff[1]);
        __syncthreads();

        bf16x8 af[4], bfv[4];
        #pragma unroll
        for (int i = 0; i < 4; ++i) {
            af[i]  = *(const bf16x8*)(lA + aoff[i]);
            bfv[i] = *(const bf16x8*)(lB + boff[i]);
        }
        #pragma unroll
        for (int mi = 0; mi < 4; ++mi)
            #pragma unroll
            for (int ni = 0; ni < 4; ++ni)
                acc[mi][ni] = __builtin_amdgcn_mfma_f32_16x16x32_bf16(
                    af[mi], bfv[ni], acc[mi][ni], 0, 0, 0);
    }

    #pragma unroll
    for (int mi = 0; mi < 4; ++mi) {
        #pragma unroll
        for (int ni = 0; ni < 4; ++ni) {
            const int col = colb + wc * 64 + ni * 16 + (ln & 15);
            #pragma unroll
            for (int reg = 0; reg < 4; ++reg) {
                const int r = row0 + wr * 64 + mi * 16 + (ln >> 4) * 4 + reg;
                if (r < M) C[(size_t)r * N + col] = f2bf_(acc[mi][ni][reg]);
            }
        }
    }
}

// ---------------------------------------------------------------------------
__global__ void f2bf_vec(const float* __restrict__ src, unsigned short* __restrict__ dst, int n4)
{
    const int i = blockIdx.x * blockDim.x + threadIdx.x;
    if (i >= n4) return;
    const float4 v = ((const float4*)src)[i];
    ushort4 o;
    o.x = f2bf_(v.x); o.y = f2bf_(v.y); o.z = f2bf_(v.z); o.w = f2bf_(v.w);
    ((ushort4*)dst)[i] = o;
}

// g: [rows,3072] bf16 = [ix|ox|ux]
__global__ void leaf_gates(const unsigned short* __restrict__ g, const float* __restrict__ b,
                           float* __restrict__ c_out, unsigned short* __restrict__ h_out,
                           int rows)
{
    const int idx = blockIdx.x * blockDim.x + threadIdx.x;
    if (idx >= rows * 256) return;
    const int r = idx >> 8, q = (idx & 255) << 2;
    const unsigned short* gr = g + (size_t)r * 3072;
    const ushort4 ix = *(const ushort4*)(gr + q);
    const ushort4 ox = *(const ushort4*)(gr + 1024 + q);
    const ushort4 ux = *(const ushort4*)(gr + 2048 + q);
    const float4 bi = *(const float4*)(b + 1024 + q);
    const float4 bo = *(const float4*)(b + 2048 + q);
    const float4 bu = *(const float4*)(b + 3072 + q);
    float4 co; ushort4 ho;
    const float c0 = sig_(bf2f_(ix.x) + bi.x) * tanhf(bf2f_(ux.x) + bu.x);
    const float c1 = sig_(bf2f_(ix.y) + bi.y) * tanhf(bf2f_(ux.y) + bu.y);
    const float c2 = sig_(bf2f_(ix.z) + bi.z) * tanhf(bf2f_(ux.z) + bu.z);
    const float c3 = sig_(bf2f_(ix.w) + bi.w) * tanhf(bf2f_(ux.w) + bu.w);
    co.x = c0; co.y = c1; co.z = c2; co.w = c3;
    ho.x = f2bf_(sig_(bf2f_(ox.x) + bo.x) * tanhf(c0));
    ho.y = f2bf_(sig_(bf2f_(ox.y) + bo.y) * tanhf(c1));
    ho.z = f2bf_(sig_(bf2f_(ox.z) + bo.z) * tanhf(c2));
    ho.w = f2bf_(sig_(bf2f_(ox.w) + bo.w) * tanhf(c3));
    *(float4*)(c_out + (size_t)r * 1024 + q) = co;
    *(ushort4*)(h_out + (size_t)r * 1024 + q) = ho;
}

// g: [rows,5120] bf16 = [ih|oh|uh|fl|fr]; c_prev [rows,2048] f32
__global__ void node_gates(const unsigned short* __restrict__ g, const float* __restrict__ b,
                           const float* __restrict__ c_prev,
                           float* __restrict__ c_out, unsigned short* __restrict__ h_bf,
                           float* __restrict__ h_f32, int rows)
{
    const int idx = blockIdx.x * blockDim.x + threadIdx.x;
    if (idx >= rows * 256) return;
    const int r = idx >> 8, q = (idx & 255) << 2;
    const unsigned short* gr = g + (size_t)r * 5120;
    const ushort4 ih = *(const ushort4*)(gr + q);
    const ushort4 oh = *(const ushort4*)(gr + 1024 + q);
    const ushort4 uh = *(const ushort4*)(gr + 2048 + q);
    const ushort4 fl = *(const ushort4*)(gr + 3072 + q);
    const ushort4 fr = *(const ushort4*)(gr + 4096 + q);
    const float4 bi = *(const float4*)(b + 1024 + q);
    const float4 bo = *(const float4*)(b + 2048 + q);
    const float4 bu = *(const float4*)(b + 3072 + q);
    const float4 bff = *(const float4*)(b + q);
    const float4 cl = *(const float4*)(c_prev + (size_t)r * 2048 + q);
    const float4 cr = *(const float4*)(c_prev + (size_t)r * 2048 + 1024 + q);

    float4 co, hv;
    const float c0 = sig_(bf2f_(ih.x) + bi.x) * tanhf(bf2f_(uh.x) + bu.x) + sig_(bf2f_(fl.x) + bff.x) * cl.x + sig_(bf2f_(fr.x) + bff.x) * cr.x;
    const float c1 = sig_(bf2f_(ih.y) + bi.y) * tanhf(bf2f_(uh.y) + bu.y) + sig_(bf2f_(fl.y) + bff.y) * cl.y + sig_(bf2f_(fr.y) + bff.y) * cr.y;
    const float c2 = sig_(bf2f_(ih.z) + bi.z) * tanhf(bf2f_(uh.z) + bu.z) + sig_(bf2f_(fl.z) + bff.z) * cl.z + sig_(bf2f_(fr.z) + bff.z) * cr.z;
    const float c3 = sig_(bf2f_(ih.w) + bi.w) * tanhf(bf2f_(uh.w) + bu.w) + sig_(bf2f_(fl.w) + bff.w) * cl.w + sig_(bf2f_(fr.w) + bff.w) * cr.w;
    co.x = c0; co.y = c1; co.z = c2; co.w = c3;
    hv.x = sig_(bf2f_(oh.x) + bo.x) * tanhf(c0);
    hv.y = sig_(bf2f_(oh.y) + bo.y) * tanhf(c1);
    hv.z = sig_(bf2f_(oh.z) + bo.z) * tanhf(c2);
    hv.w = sig_(bf2f_(oh.w) + bo.w) * tanhf(c3);
    *(float4*)(c_out + (size_t)r * 1024 + q) = co;
    ushort4 ho;
    ho.x = f2bf_(hv.x); ho.y = f2bf_(hv.y); ho.z = f2bf_(hv.z); ho.w = f2bf_(hv.w);
    *(ushort4*)(h_bf + (size_t)r * 1024 + q) = ho;
    if (h_f32) *(float4*)(h_f32 + (size_t)r * 1024 + q) = hv;
}

extern "C" void kernel_launch(void* const* d_in, const int* in_sizes, int n_in,
                              void* d_out, int out_size, void* d_ws, size_t ws_size,
                              hipStream_t stream)
{
    const float* inputs  = (const float*)d_in[0];  // [16384,1024]
    const float* w_fioux = (const float*)d_in[1];  // [4096,1024]
    const float* b_fioux = (const float*)d_in[2];  // [4096]
    const float* w_iouh  = (const float*)d_in[3];  // [3072,2048]
    const float* w_fh    = (const float*)d_in[4];  // [2048,2048]
    float* out = (float*)d_out;                    // [32,1024]

    // ---- ws layout (~228.6 MB) ----
    float* ws = (float*)d_ws;
    float*          c_a  = ws;                                    // 16777216 f32
    float*          c_b  = c_a + (size_t)16777216;                //  8388608 f32
    unsigned short* h_a  = (unsigned short*)(c_b + (size_t)8388608); // 16777216 bf16
    unsigned short* h_b  = h_a + (size_t)16777216;                //  8388608 bf16
    unsigned short* wfx  = h_b + (size_t)8388608;                 //  3145728 bf16
    unsigned short* wcat = wfx + (size_t)3145728;                 // 10485760 bf16
    unsigned short* gbuf = wcat + (size_t)10485760;               // 25165824 bf16
    unsigned short* x_bf = (unsigned short*)c_b;                  // alias (safe: see order)

    // ---- one-time fp32 -> bf16 conversions ----
    f2bf_vec<<<16384, 256, 0, stream>>>(inputs, x_bf, 16384 * 256);
    f2bf_vec<<<3072, 256, 0, stream>>>(w_fioux + (size_t)1024 * 1024, wfx, 3072 * 256);
    f2bf_vec<<<6144, 256, 0, stream>>>(w_iouh, wcat, 3072 * 512);
    f2bf_vec<<<4096, 256, 0, stream>>>(w_fh, wcat + (size_t)3072 * 2048, 2048 * 512);

    // ---- leaf level: 2 x 8192 rows, K=1024, N=3072 ----
    for (int r0 = 0; r0 < 16384; r0 += 8192) {
        gemm256<<<dim3(3072 / 256, 8192 / 256), 512, 0, stream>>>(
            x_bf + (size_t)r0 * 1024, wfx, gbuf, 8192, 3072, 1024);
        leaf_gates<<<8192, 256, 0, stream>>>(
            gbuf, b_fioux, c_a + (size_t)r0 * 1024, h_a + (size_t)r0 * 1024, 8192);
    }

    // ---- internal levels: n = 256 .. 1 ----
    unsigned short *hp = h_a, *hn = h_b;
    float *cp = c_a, *cn = c_b;
    for (int n = 256; n >= 1; n >>= 1) {
        const int rows = 32 * n;
        const int CH = (rows > 4096) ? 4096 : rows;
        for (int r0 = 0; r0 < rows; r0 += CH) {
            const int m = (rows - r0 < CH) ? (rows - r0) : CH;
            if (m >= 2048) {
                gemm256<<<dim3(5120 / 256, m / 256), 512, 0, stream>>>(
                    hp + (size_t)r0 * 2048, wcat, gbuf, m, 5120, 2048);
            } else {
                gemm128<<<dim3(5120 / 128, (m + 127) / 128), 256, 0, stream>>>(
                    hp + (size_t)r0 * 2048, wcat, gbuf, m, 5120, 2048);
            }
            node_gates<<<(m * 256 + 255) / 256, 256, 0, stream>>>(
                gbuf, b_fioux, cp + (size_t)r0 * 2048,
                cn + (size_t)r0 * 1024, hn + (size_t)r0 * 1024,
                (n == 1) ? out : nullptr, m);
        }
        unsigned short* th = hp; hp = hn; hn = th;
        float* tc = cp; cp = cn; cn = tc;
    }
    (void)in_sizes; (void)n_in; (void)out_size; (void)ws_size;
}

// Round 4
// 783.997 us; speedup vs baseline: 12.0619x; 1.1779x over previous
//
#include <hip/hip_runtime.h>
#include <cstdint>
#include <cstddef>

// BinaryTreeLSTM — 256^2 8-wave pipelined bf16 MFMA GEMM (with split-K) + gates.
// Leaf:     [i|o|u] = x_bf @ wfx_bf.T          (N=3072; f-gate dead at leaves)
// Internal: [ih|oh|uh|fl|fr] = h_prev(bf16,[m,2048]) @ wcat_bf.T  (N=5120)
// h, c stored bf16; gate pre-activations / split-K partials bf16; sums fp32.

typedef __attribute__((ext_vector_type(8))) short bf16x8;
typedef __attribute__((ext_vector_type(4))) float f32x4;

__device__ __forceinline__ float sig_(float x) { return 1.0f / (1.0f + __expf(-x)); }

__device__ __forceinline__ unsigned short f2bf_(float x) {
    union { float f; uint32_t u; } v; v.f = x;
    uint32_t r = v.u + 0x7fffu + ((v.u >> 16) & 1u);   // RNE
    return (unsigned short)(r >> 16);
}
__device__ __forceinline__ float bf2f_(unsigned short u) {
    union { uint32_t u; float f; } v; v.u = ((uint32_t)u) << 16; return v.f;
}

#define GL16(g, l) __builtin_amdgcn_global_load_lds( \
    (const __attribute__((address_space(1))) void*)(g), \
    (__attribute__((address_space(3))) void*)(l), 16, 0, 0)

// ---------------------------------------------------------------------------
// gemm256: partial[bz][M,N] bf16 = A[M, k-range] @ W[N, k-range]^T
//   A,W row stride = lda (total K). z-slice bz covers k in [bz*Klen, +Klen).
//   N multiple of 256; Klen multiple of 64, Klen/64 >= 3. Any M (rows clamp).
//   512 thr = 8 waves (2Mx4N), wave tile 128x64. 4 circular k-half LDS slots
//   per operand ([256][32] bf16, XOR-swizzled), 3-ahead prefetch,
//   steady-state s_waitcnt vmcnt(8), raw s_barrier. XCD-bijective id remap.
// ---------------------------------------------------------------------------
__global__ __launch_bounds__(512, 2)
void gemm256(const unsigned short* __restrict__ A,
             const unsigned short* __restrict__ W,
             unsigned short* __restrict__ C, int M, int N, int lda, int Klen)
{
    __shared__ unsigned short lA[4 * 8192];   // 64 KB
    __shared__ unsigned short lB[4 * 8192];   // 64 KB

    // ---- bijective XCD-aware remap of the flattened block id (m204) ----
    const int gx = gridDim.x, gy = gridDim.y;
    int id = blockIdx.x + gx * (blockIdx.y + gy * blockIdx.z);
    {
        const int nwg = gx * gy * gridDim.z;
        const int q = nwg >> 3, r = nwg & 7, x = id & 7, i = id >> 3;
        id = (x < r ? x * (q + 1) : r * (q + 1) + (x - r) * q) + i;
    }
    const int bz  = id / (gx * gy);
    const int rem = id - bz * gx * gy;
    const int by  = rem / gx;
    const int bx  = rem - by * gx;

    const int tid = threadIdx.x;
    const int ln  = tid & 63;
    const int wv  = tid >> 6;        // 0..7
    const int wrp = wv >> 2;         // 0..1 : output rows wrp*128..+127
    const int wcp = wv & 3;          // 0..3 : output cols wcp*64..+63
    const int row0 = by * 256;
    const int colb = bx * 256;
    const int kbase = bz * Klen;
    C += (size_t)bz * M * N;         // this split's partial slice

    // staging: thread covers slot bytes tid*16 and 8192+tid*16
    const int rowS = tid >> 2;                        // 0..127 (2nd load: +128)
    const int gS   = (tid & 3) ^ ((tid >> 3) & 3);    // pre-swizzled source slot
    const unsigned short* a0 = A + (size_t)min(row0 + rowS,       M - 1) * lda + kbase + gS * 8;
    const unsigned short* a1 = A + (size_t)min(row0 + rowS + 128, M - 1) * lda + kbase + gS * 8;
    const unsigned short* b0 = W + (size_t)(colb + rowS)       * lda + kbase + gS * 8;
    const unsigned short* b1 = W + (size_t)(colb + rowS + 128) * lda + kbase + gS * 8;
    const int ld0 = tid * 8;          // ushort offset within slot (linear dest)
    const int ld1 = tid * 8 + 4096;

    // fragment read offsets (ushort units, slot-relative, XOR-swizzled)
    int offA[8], offB[4];
    #pragma unroll
    for (int i = 0; i < 8; ++i) {
        const int r = wrp * 128 + i * 16 + (ln & 15);
        offA[i] = r * 32 + ((ln >> 4) ^ ((r >> 1) & 3)) * 8;
    }
    #pragma unroll
    for (int i = 0; i < 4; ++i) {
        const int r = wcp * 64 + i * 16 + (ln & 15);
        offB[i] = r * 32 + ((ln >> 4) ^ ((r >> 1) & 3)) * 8;
    }

    f32x4 acc[8][4] = {};
    const int NT = Klen >> 6;

#define ISSUE_KH(kh) do { \
    const int _sl = (kh) & 3; \
    const size_t _ko = (size_t)(kh) * 32; \
    GL16(a0 + _ko, lA + _sl * 8192 + ld0); \
    GL16(a1 + _ko, lA + _sl * 8192 + ld1); \
    GL16(b0 + _ko, lB + _sl * 8192 + ld0); \
    GL16(b1 + _ko, lB + _sl * 8192 + ld1); \
} while (0)

#define PHASE(SLOT, KH, DOISS, WAITN, DOBAR) do { \
    const unsigned short* _pa = lA + (SLOT) * 8192; \
    const unsigned short* _pb = lB + (SLOT) * 8192; \
    bf16x8 _af[8], _bf[4]; \
    _Pragma("unroll") for (int _i = 0; _i < 4; ++_i) _bf[_i] = *(const bf16x8*)(_pb + offB[_i]); \
    _Pragma("unroll") for (int _i = 0; _i < 4; ++_i) _af[_i] = *(const bf16x8*)(_pa + offA[_i]); \
    if (DOISS) ISSUE_KH(KH); \
    __builtin_amdgcn_s_setprio(1); \
    _Pragma("unroll") for (int _m = 0; _m < 4; ++_m) \
        _Pragma("unroll") for (int _n = 0; _n < 4; ++_n) \
            acc[_m][_n] = __builtin_amdgcn_mfma_f32_16x16x32_bf16(_af[_m], _bf[_n], acc[_m][_n], 0, 0, 0); \
    __builtin_amdgcn_s_setprio(0); \
    _Pragma("unroll") for (int _i = 4; _i < 8; ++_i) _af[_i] = *(const bf16x8*)(_pa + offA[_i]); \
    __builtin_amdgcn_s_setprio(1); \
    _Pragma("unroll") for (int _m = 4; _m < 8; ++_m) \
        _Pragma("unroll") for (int _n = 0; _n < 4; ++_n) \
            acc[_m][_n] = __builtin_amdgcn_mfma_f32_16x16x32_bf16(_af[_m], _bf[_n], acc[_m][_n], 0, 0, 0); \
    __builtin_amdgcn_s_setprio(0); \
    if ((WAITN) == 8)      asm volatile("s_waitcnt vmcnt(8)" ::: "memory"); \
    else if ((WAITN) == 4) asm volatile("s_waitcnt vmcnt(4)" ::: "memory"); \
    else if ((WAITN) == 0) asm volatile("s_waitcnt vmcnt(0)" ::: "memory"); \
    if (DOBAR) asm volatile("s_barrier" ::: "memory"); \
} while (0)

    // prologue: stage k-halves 0,1,2 ; ensure k-half 0 landed (8 stay in flight)
    ISSUE_KH(0); ISSUE_KH(1); ISSUE_KH(2);
    asm volatile("s_waitcnt vmcnt(8)" ::: "memory");
    asm volatile("s_barrier" ::: "memory");

    for (int t = 0; t <= NT - 3; ++t) {
        const int ph = 2 * t;
        PHASE((ph) & 3,     ph + 3, 1, 8, 1);
        PHASE((ph + 1) & 3, ph + 4, 1, 8, 1);
    }
    {
        const int ph = 2 * NT - 4;
        PHASE((ph) & 3,     ph + 3, 1,  8, 1);   // issues last k-half 2NT-1
        PHASE((ph + 1) & 3, 0,      0,  4, 1);
        PHASE((ph + 2) & 3, 0,      0,  0, 1);
        PHASE((ph + 3) & 3, 0,      0, -1, 0);
    }
#undef PHASE
#undef ISSUE_KH

    // epilogue: C/D map col=lane&15, row=(lane>>4)*4+reg  [m89/m91]
    #pragma unroll
    for (int mi = 0; mi < 8; ++mi) {
        #pragma unroll
        for (int ni = 0; ni < 4; ++ni) {
            const int col = colb + wcp * 64 + ni * 16 + (ln & 15);
            #pragma unroll
            for (int rg = 0; rg < 4; ++rg) {
                const int r = row0 + wrp * 128 + mi * 16 + (ln >> 4) * 4 + rg;
                if (r < M) C[(size_t)r * N + col] = f2bf_(acc[mi][ni][rg]);
            }
        }
    }
}

// ---------------------------------------------------------------------------
__global__ void f2bf_vec(const float* __restrict__ src, unsigned short* __restrict__ dst, int n4)
{
    const int i = blockIdx.x * blockDim.x + threadIdx.x;
    if (i >= n4) return;
    const float4 v = ((const float4*)src)[i];
    ushort4 o;
    o.x = f2bf_(v.x); o.y = f2bf_(v.y); o.z = f2bf_(v.z); o.w = f2bf_(v.w);
    ((ushort4*)dst)[i] = o;
}

// g: [rows,3072] bf16 = [ix|ox|ux]; c_out, h_out bf16
__global__ void leaf_gates(const unsigned short* __restrict__ g, const float* __restrict__ b,
                           unsigned short* __restrict__ c_out, unsigned short* __restrict__ h_out,
                           int rows)
{
    const int idx = blockIdx.x * blockDim.x + threadIdx.x;
    if (idx >= rows * 256) return;
    const int r = idx >> 8, q = (idx & 255) << 2;
    const unsigned short* gr = g + (size_t)r * 3072;
    const ushort4 ix = *(const ushort4*)(gr + q);
    const ushort4 ox = *(const ushort4*)(gr + 1024 + q);
    const ushort4 ux = *(const ushort4*)(gr + 2048 + q);
    const float* bi = b + 1024 + q;
    const float* bo = b + 2048 + q;
    const float* bu = b + 3072 + q;
    ushort4 co, ho;
    const float c0 = sig_(bf2f_(ix.x) + bi[0]) * tanhf(bf2f_(ux.x) + bu[0]);
    const float c1 = sig_(bf2f_(ix.y) + bi[1]) * tanhf(bf2f_(ux.y) + bu[1]);
    const float c2 = sig_(bf2f_(ix.z) + bi[2]) * tanhf(bf2f_(ux.z) + bu[2]);
    const float c3 = sig_(bf2f_(ix.w) + bi[3]) * tanhf(bf2f_(ux.w) + bu[3]);
    co.x = f2bf_(c0); co.y = f2bf_(c1); co.z = f2bf_(c2); co.w = f2bf_(c3);
    ho.x = f2bf_(sig_(bf2f_(ox.x) + bo[0]) * tanhf(c0));
    ho.y = f2bf_(sig_(bf2f_(ox.y) + bo[1]) * tanhf(c1));
    ho.z = f2bf_(sig_(bf2f_(ox.z) + bo[2]) * tanhf(c2));
    ho.w = f2bf_(sig_(bf2f_(ox.w) + bo[3]) * tanhf(c3));
    *(ushort4*)(c_out + (size_t)r * 1024 + q) = co;
    *(ushort4*)(h_out + (size_t)r * 1024 + q) = ho;
}

__device__ __forceinline__ void acc4_(float* v, ushort4 u) {
    v[0] += bf2f_(u.x); v[1] += bf2f_(u.y); v[2] += bf2f_(u.z); v[3] += bf2f_(u.w);
}

// g: S bf16 partials of [rows,5120] = [ih|oh|uh|fl|fr], stride sstride elems.
// c_prev bf16 [rows,2048]; outputs: c_out/h_bf bf16, optional h_f32.
__global__ void node_gates(const unsigned short* __restrict__ g, int S, size_t sstride,
                           const float* __restrict__ b,
                           const unsigned short* __restrict__ c_prev,
                           unsigned short* __restrict__ c_out,
                           unsigned short* __restrict__ h_bf,
                           float* __restrict__ h_f32, int rows)
{
    const int idx = blockIdx.x * blockDim.x + threadIdx.x;
    if (idx >= rows * 256) return;
    const int r = idx >> 8, q = (idx & 255) << 2;
    float vi[4] = {}, vo[4] = {}, vu[4] = {}, vfl[4] = {}, vfr[4] = {};
    const unsigned short* gr = g + (size_t)r * 5120 + q;
    for (int s = 0; s < S; ++s, gr += sstride) {
        acc4_(vi,  *(const ushort4*)(gr));
        acc4_(vo,  *(const ushort4*)(gr + 1024));
        acc4_(vu,  *(const ushort4*)(gr + 2048));
        acc4_(vfl, *(const ushort4*)(gr + 3072));
        acc4_(vfr, *(const ushort4*)(gr + 4096));
    }
    const float* bi = b + 1024 + q;
    const float* bo = b + 2048 + q;
    const float* bu = b + 3072 + q;
    const float* bff = b + q;
    const ushort4 clu = *(const ushort4*)(c_prev + (size_t)r * 2048 + q);
    const ushort4 cru = *(const ushort4*)(c_prev + (size_t)r * 2048 + 1024 + q);
    const float cl[4] = { bf2f_(clu.x), bf2f_(clu.y), bf2f_(clu.z), bf2f_(clu.w) };
    const float cr[4] = { bf2f_(cru.x), bf2f_(cru.y), bf2f_(cru.z), bf2f_(cru.w) };

    ushort4 co, ho;
    float hv[4];
    float cv[4];
    #pragma unroll
    for (int e = 0; e < 4; ++e) {
        const float c = sig_(vi[e] + bi[e]) * tanhf(vu[e] + bu[e])
                      + sig_(vfl[e] + bff[e]) * cl[e]
                      + sig_(vfr[e] + bff[e]) * cr[e];
        cv[e] = c;
        hv[e] = sig_(vo[e] + bo[e]) * tanhf(c);
    }
    co.x = f2bf_(cv[0]); co.y = f2bf_(cv[1]); co.z = f2bf_(cv[2]); co.w = f2bf_(cv[3]);
    ho.x = f2bf_(hv[0]); ho.y = f2bf_(hv[1]); ho.z = f2bf_(hv[2]); ho.w = f2bf_(hv[3]);
    *(ushort4*)(c_out + (size_t)r * 1024 + q) = co;
    *(ushort4*)(h_bf + (size_t)r * 1024 + q) = ho;
    if (h_f32) {
        float4 hf; hf.x = hv[0]; hf.y = hv[1]; hf.z = hv[2]; hf.w = hv[3];
        *(float4*)(h_f32 + (size_t)r * 1024 + q) = hf;
    }
}

extern "C" void kernel_launch(void* const* d_in, const int* in_sizes, int n_in,
                              void* d_out, int out_size, void* d_ws, size_t ws_size,
                              hipStream_t stream)
{
    const float* inputs  = (const float*)d_in[0];  // [16384,1024]
    const float* w_fioux = (const float*)d_in[1];  // [4096,1024]
    const float* b_fioux = (const float*)d_in[2];  // [4096]
    const float* w_iouh  = (const float*)d_in[3];  // [3072,2048]
    const float* w_fh    = (const float*)d_in[4];  // [2048,2048]
    float* out = (float*)d_out;                    // [32,1024]

    // ---- ws layout, bf16 units (228.6 MB total == round-3 proven size) ----
    unsigned short* us   = (unsigned short*)d_ws;
    unsigned short* c_a  = us;                          // 16777216
    unsigned short* c_b  = c_a + (size_t)16777216;      //  8388608
    unsigned short* h_a  = c_b + (size_t)8388608;       // 16777216
    unsigned short* h_b  = h_a + (size_t)16777216;      //  8388608
    unsigned short* wfx  = h_b + (size_t)8388608;       //  3145728
    unsigned short* wcat = wfx + (size_t)3145728;       // 10485760
    unsigned short* gbuf = wcat + (size_t)10485760;     // 50331648 (100.7 MB)
    unsigned short* x_bf = c_a;   // alias: x dead before leaf_gates writes c_a

    // ---- one-time fp32 -> bf16 conversions ----
    f2bf_vec<<<16384, 256, 0, stream>>>(inputs, x_bf, 4194304);
    f2bf_vec<<<3072, 256, 0, stream>>>(w_fioux + (size_t)1024 * 1024, wfx, 786432);
    f2bf_vec<<<6144, 256, 0, stream>>>(w_iouh, wcat, 1572864);
    f2bf_vec<<<4096, 256, 0, stream>>>(w_fh, wcat + (size_t)3072 * 2048, 1048576);

    // ---- leaf level: single dispatch, 16384 rows, K=1024, N=3072 ----
    gemm256<<<dim3(12, 64, 1), 512, 0, stream>>>(x_bf, wfx, gbuf, 16384, 3072, 1024, 1024);
    leaf_gates<<<16384, 256, 0, stream>>>(gbuf, b_fioux, c_a, h_a, 16384);

    // ---- internal levels: n = 256 .. 1, single dispatch each, split-K tail ----
    unsigned short *hp = h_a, *cp = c_a, *hn = h_b, *cn = c_b;
    for (int n = 256; n >= 1; n >>= 1) {
        const int m = 32 * n;
        int S;
        if (m >= 8192)      S = 1;   // 640 blocks
        else if (m >= 4096) S = 2;   // 640 blocks (Klen=1024)
        else if (m >= 2048) S = 1;   // 160 blocks
        else if (m >= 512)  S = 4;   // Klen=512
        else                S = 8;   // Klen=256
        const int Klen = 2048 / S;
        gemm256<<<dim3(20, (m + 255) / 256, S), 512, 0, stream>>>(
            hp, wcat, gbuf, m, 5120, 2048, Klen);
        node_gates<<<m, 256, 0, stream>>>(
            gbuf, S, (size_t)m * 5120, b_fioux, cp, cn, hn,
            (n == 1) ? out : nullptr, m);
        unsigned short* t;
        t = hp; hp = hn; hn = t;
        t = cp; cp = cn; cn = t;
    }
    (void)in_sizes; (void)n_in; (void)out_size; (void)ws_size;
}

// Round 5
// 736.369 us; speedup vs baseline: 12.8421x; 1.0647x over previous
//
#include <hip/hip_runtime.h>
#include <cstdint>
#include <cstddef>

// BinaryTreeLSTM — pipelined bf16 MFMA GEMMs, fused gate epilogue on big levels.
// Leaf:     [i|o|u] = x_bf @ wfx.T (N=3072), then leaf_gates.
// n=256/64: gemm320f: BN=320 gate-grouped tiles (wcatP), gates fused in epilogue.
// n<=32:    gemm256 split-K into gbuf (bf16 partials) + node_gates.
// Schedule (both GEMMs): per K=32 phase: reads; issue; vmcnt(8); barrier;
// lgkmcnt(0); MFMA clusters; barrier.  4 circular LDS slots, lookahead 3.

typedef __attribute__((ext_vector_type(8))) short bf16x8;
typedef __attribute__((ext_vector_type(4))) float f32x4;

__device__ __forceinline__ float sig_(float x) { return 1.0f / (1.0f + __expf(-x)); }

__device__ __forceinline__ unsigned short f2bf_(float x) {
    union { float f; uint32_t u; } v; v.f = x;
    uint32_t r = v.u + 0x7fffu + ((v.u >> 16) & 1u);   // RNE
    return (unsigned short)(r >> 16);
}
__device__ __forceinline__ float bf2f_(unsigned short u) {
    union { uint32_t u; float f; } v; v.u = ((uint32_t)u) << 16; return v.f;
}

#define GL16(g, l) __builtin_amdgcn_global_load_lds( \
    (const __attribute__((address_space(1))) void*)(g), \
    (__attribute__((address_space(3))) void*)(l), 16, 0, 0)

#define PHASE_WAITS(p, P) do { \
    if ((p) <= (P) - 4)      asm volatile("s_waitcnt vmcnt(8)" ::: "memory"); \
    else if ((p) == (P) - 3) asm volatile("s_waitcnt vmcnt(4)" ::: "memory"); \
    else if ((p) == (P) - 2) asm volatile("s_waitcnt vmcnt(0)" ::: "memory"); \
    asm volatile("s_barrier" ::: "memory"); \
    asm volatile("s_waitcnt lgkmcnt(0)" ::: "memory"); \
    __builtin_amdgcn_sched_barrier(0); \
} while (0)

// ---------------------------------------------------------------------------
// gemm256: partial[bz][M,N] bf16 = A[M, kr] @ W[N, kr]^T ; kr = [bz*Klen,+Klen)
// ---------------------------------------------------------------------------
__global__ __launch_bounds__(512, 2)
void gemm256(const unsigned short* __restrict__ A,
             const unsigned short* __restrict__ W,
             unsigned short* __restrict__ C, int M, int N, int lda, int Klen)
{
    __shared__ unsigned short lA[4 * 8192];   // 64 KB
    __shared__ unsigned short lB[4 * 8192];   // 64 KB

    const int gx = gridDim.x, gy = gridDim.y;
    int id = blockIdx.x + gx * (blockIdx.y + gy * blockIdx.z);
    {
        const int nwg = gx * gy * gridDim.z;
        const int q = nwg >> 3, r = nwg & 7, x = id & 7, i = id >> 3;
        id = (x < r ? x * (q + 1) : r * (q + 1) + (x - r) * q) + i;
    }
    const int bz  = id / (gx * gy);
    const int rem = id - bz * gx * gy;
    const int by  = rem / gx;
    const int bx  = rem - by * gx;

    const int tid = threadIdx.x;
    const int ln  = tid & 63;
    const int wv  = tid >> 6;
    const int wrp = wv >> 2;
    const int wcp = wv & 3;
    const int row0 = by * 256;
    const int colb = bx * 256;
    const int kbase = bz * Klen;
    C += (size_t)bz * M * N;

    const int rowS = tid >> 2;
    const int gS   = (tid & 3) ^ ((tid >> 3) & 3);
    const unsigned short* a0 = A + (size_t)min(row0 + rowS,       M - 1) * lda + kbase + gS * 8;
    const unsigned short* a1 = A + (size_t)min(row0 + rowS + 128, M - 1) * lda + kbase + gS * 8;
    const unsigned short* b0 = W + (size_t)(colb + rowS)       * lda + kbase + gS * 8;
    const unsigned short* b1 = W + (size_t)(colb + rowS + 128) * lda + kbase + gS * 8;
    const int ld0 = tid * 8;
    const int ld1 = tid * 8 + 4096;

    int offA[8], offB[4];
    #pragma unroll
    for (int i = 0; i < 8; ++i) {
        const int r = wrp * 128 + i * 16 + (ln & 15);
        offA[i] = r * 32 + ((ln >> 4) ^ ((r >> 1) & 3)) * 8;
    }
    #pragma unroll
    for (int i = 0; i < 4; ++i) {
        const int r = wcp * 64 + i * 16 + (ln & 15);
        offB[i] = r * 32 + ((ln >> 4) ^ ((r >> 1) & 3)) * 8;
    }

    f32x4 acc[8][4] = {};
    const int P = Klen >> 5;   // K=32 phases

#define ISSUE_KH(kh) do { \
    const int _sl = (kh) & 3; \
    const size_t _ko = (size_t)(kh) * 32; \
    GL16(a0 + _ko, lA + _sl * 8192 + ld0); \
    GL16(a1 + _ko, lA + _sl * 8192 + ld1); \
    GL16(b0 + _ko, lB + _sl * 8192 + ld0); \
    GL16(b1 + _ko, lB + _sl * 8192 + ld1); \
} while (0)

    ISSUE_KH(0); ISSUE_KH(1); ISSUE_KH(2);
    asm volatile("s_waitcnt vmcnt(8)" ::: "memory");
    asm volatile("s_barrier" ::: "memory");

    for (int p = 0; p < P; ++p) {
        const unsigned short* pa = lA + (p & 3) * 8192;
        const unsigned short* pb = lB + (p & 3) * 8192;
        bf16x8 bf[4], af[4];
        #pragma unroll
        for (int i = 0; i < 4; ++i) bf[i] = *(const bf16x8*)(pb + offB[i]);
        #pragma unroll
        for (int i = 0; i < 4; ++i) af[i] = *(const bf16x8*)(pa + offA[i]);
        if (p <= P - 4) ISSUE_KH(p + 3);
        PHASE_WAITS(p, P);
        __builtin_amdgcn_s_setprio(1);
        #pragma unroll
        for (int m = 0; m < 4; ++m)
            #pragma unroll
            for (int n = 0; n < 4; ++n)
                acc[m][n] = __builtin_amdgcn_mfma_f32_16x16x32_bf16(af[m], bf[n], acc[m][n], 0, 0, 0);
        __builtin_amdgcn_s_setprio(0);
        bf16x8 ag[4];
        #pragma unroll
        for (int i = 0; i < 4; ++i) ag[i] = *(const bf16x8*)(pa + offA[4 + i]);
        asm volatile("s_waitcnt lgkmcnt(0)" ::: "memory");
        __builtin_amdgcn_sched_barrier(0);
        __builtin_amdgcn_s_setprio(1);
        #pragma unroll
        for (int m = 0; m < 4; ++m)
            #pragma unroll
            for (int n = 0; n < 4; ++n)
                acc[4 + m][n] = __builtin_amdgcn_mfma_f32_16x16x32_bf16(ag[m], bf[n], acc[4 + m][n], 0, 0, 0);
        __builtin_amdgcn_s_setprio(0);
        asm volatile("s_barrier" ::: "memory");
    }
#undef ISSUE_KH

    #pragma unroll
    for (int mi = 0; mi < 8; ++mi) {
        #pragma unroll
        for (int ni = 0; ni < 4; ++ni) {
            const int col = colb + wcp * 64 + ni * 16 + (ln & 15);
            #pragma unroll
            for (int rg = 0; rg < 4; ++rg) {
                const int r = row0 + wrp * 128 + mi * 16 + (ln >> 4) * 4 + rg;
                if (r < M) C[(size_t)r * N + col] = f2bf_(acc[mi][ni][rg]);
            }
        }
    }
}

// ---------------------------------------------------------------------------
// gemm320f: fused internal level. A[M,2048]bf16, Wp[5120,2048]bf16 permuted
// (16 groups of 320 rows = [ih|oh|uh|fl|fr] for 64 consecutive j).
// Block: 256 rows x 320 cols. Wave (wrp,wcp): rows 128*wrp+.., j-sub wcp*16.
// acc[mi][g] = gate g pre-activation of element (r, j). Epilogue: gates+c,h.
// ---------------------------------------------------------------------------
__global__ __launch_bounds__(512, 2)
void gemm320f(const unsigned short* __restrict__ A,
              const unsigned short* __restrict__ Wp,
              const float* __restrict__ b,
              const unsigned short* __restrict__ c_prev,
              unsigned short* __restrict__ c_out,
              unsigned short* __restrict__ h_out,
              int M)
{
    __shared__ unsigned short lA[4 * 8192];    // 64 KB
    __shared__ unsigned short lB[4 * 10240];   // 80 KB
    const int lda = 2048;

    const int gx = gridDim.x, gy = gridDim.y;
    int id = blockIdx.x + gx * blockIdx.y;
    {
        const int nwg = gx * gy;
        const int q = nwg >> 3, r = nwg & 7, x = id & 7, i = id >> 3;
        id = (x < r ? x * (q + 1) : r * (q + 1) + (x - r) * q) + i;
    }
    const int by = id / gx;
    const int bx = id - by * gx;

    const int tid = threadIdx.x;
    const int ln  = tid & 63;
    const int wv  = tid >> 6;
    const int wrp = wv >> 2;
    const int wcp = wv & 3;
    const int row0 = by * 256;
    const int colb = bx * 320;

    const int rowS = tid >> 2;
    const int gS   = (tid & 3) ^ ((tid >> 3) & 3);
    const unsigned short* a0 = A + (size_t)min(row0 + rowS,       M - 1) * lda + gS * 8;
    const unsigned short* a1 = A + (size_t)min(row0 + rowS + 128, M - 1) * lda + gS * 8;
    const unsigned short* w0 = Wp + (size_t)(colb + rowS)       * lda + gS * 8;
    const unsigned short* w1 = Wp + (size_t)(colb + rowS + 128) * lda + gS * 8;
    const unsigned short* w2 = Wp + (size_t)(colb + 256 + ((tid & 255) >> 2)) * lda + gS * 8;
    const int ld0 = tid * 8;
    const int ld1 = tid * 8 + 4096;
    const int ld2 = (tid & 255) * 8 + 8192;

    int offA[8], offB[5];
    #pragma unroll
    for (int i = 0; i < 8; ++i) {
        const int r = wrp * 128 + i * 16 + (ln & 15);
        offA[i] = r * 32 + ((ln >> 4) ^ ((r >> 1) & 3)) * 8;
    }
    #pragma unroll
    for (int g = 0; g < 5; ++g) {
        const int r = g * 64 + wcp * 16 + (ln & 15);
        offB[g] = r * 32 + ((ln >> 4) ^ ((r >> 1) & 3)) * 8;
    }

    f32x4 acc[8][5] = {};
    const int P = 64;   // 2048 / 32

#define ISSUE_F(kh) do { \
    const int _sl = (kh) & 3; \
    const size_t _ko = (size_t)(kh) * 32; \
    GL16(a0 + _ko, lA + _sl * 8192 + ld0); \
    GL16(a1 + _ko, lA + _sl * 8192 + ld1); \
    GL16(w0 + _ko, lB + _sl * 10240 + ld0); \
    GL16(w1 + _ko, lB + _sl * 10240 + ld1); \
    if (wv < 4) GL16(w2 + _ko, lB + _sl * 10240 + ld2); \
} while (0)

    ISSUE_F(0); ISSUE_F(1); ISSUE_F(2);
    asm volatile("s_waitcnt vmcnt(8)" ::: "memory");
    asm volatile("s_barrier" ::: "memory");

    for (int p = 0; p < P; ++p) {
        const unsigned short* pa = lA + (p & 3) * 8192;
        const unsigned short* pb = lB + (p & 3) * 10240;
        bf16x8 bf[5], af[4];
        #pragma unroll
        for (int g = 0; g < 5; ++g) bf[g] = *(const bf16x8*)(pb + offB[g]);
        #pragma unroll
        for (int i = 0; i < 4; ++i) af[i] = *(const bf16x8*)(pa + offA[i]);
        if (p <= P - 4) ISSUE_F(p + 3);
        PHASE_WAITS(p, P);
        __builtin_amdgcn_s_setprio(1);
        #pragma unroll
        for (int m = 0; m < 4; ++m)
            #pragma unroll
            for (int g = 0; g < 5; ++g)
                acc[m][g] = __builtin_amdgcn_mfma_f32_16x16x32_bf16(af[m], bf[g], acc[m][g], 0, 0, 0);
        __builtin_amdgcn_s_setprio(0);
        bf16x8 ag[4];
        #pragma unroll
        for (int i = 0; i < 4; ++i) ag[i] = *(const bf16x8*)(pa + offA[4 + i]);
        asm volatile("s_waitcnt lgkmcnt(0)" ::: "memory");
        __builtin_amdgcn_sched_barrier(0);
        __builtin_amdgcn_s_setprio(1);
        #pragma unroll
        for (int m = 0; m < 4; ++m)
            #pragma unroll
            for (int g = 0; g < 5; ++g)
                acc[4 + m][g] = __builtin_amdgcn_mfma_f32_16x16x32_bf16(ag[m], bf[g], acc[4 + m][g], 0, 0, 0);
        __builtin_amdgcn_s_setprio(0);
        asm volatile("s_barrier" ::: "memory");
    }
#undef ISSUE_F

    // ---- fused gate epilogue ----
    const int jg = bx * 64 + wcp * 16 + (ln & 15);   // global j in [0,1024)
    const float bi = b[1024 + jg];
    const float bo = b[2048 + jg];
    const float bu = b[3072 + jg];
    const float bff = b[jg];
    #pragma unroll
    for (int mi = 0; mi < 8; ++mi) {
        #pragma unroll
        for (int rg = 0; rg < 4; ++rg) {
            const int r = row0 + wrp * 128 + mi * 16 + (ln >> 4) * 4 + rg;
            if (r < M) {
                const float cl = bf2f_(c_prev[(size_t)r * 2048 + jg]);
                const float cr = bf2f_(c_prev[(size_t)r * 2048 + 1024 + jg]);
                const float iv = sig_(acc[mi][0][rg] + bi);
                const float ov = sig_(acc[mi][1][rg] + bo);
                const float uv = tanhf(acc[mi][2][rg] + bu);
                const float flv = sig_(acc[mi][3][rg] + bff);
                const float frv = sig_(acc[mi][4][rg] + bff);
                const float c = iv * uv + flv * cl + frv * cr;
                const float h = ov * tanhf(c);
                c_out[(size_t)r * 1024 + jg] = f2bf_(c);
                h_out[(size_t)r * 1024 + jg] = f2bf_(h);
            }
        }
    }
}

// ---------------------------------------------------------------------------
__global__ void f2bf_vec(const float* __restrict__ src, unsigned short* __restrict__ dst, int n4)
{
    const int i = blockIdx.x * blockDim.x + threadIdx.x;
    if (i >= n4) return;
    const float4 v = ((const float4*)src)[i];
    ushort4 o;
    o.x = f2bf_(v.x); o.y = f2bf_(v.y); o.z = f2bf_(v.z); o.w = f2bf_(v.w);
    ((ushort4*)dst)[i] = o;
}

// wcatP[rp, :] for rp = t*320 + g*64 + jj  <-  gate-g weight row (t*64+jj)
__global__ void build_wcatp(const float* __restrict__ w_iouh, const float* __restrict__ w_fh,
                            unsigned short* __restrict__ dst, int total4)
{
    const int idx = blockIdx.x * blockDim.x + threadIdx.x;
    if (idx >= total4) return;
    const int rp = idx >> 9;            // 0..5119
    const int c4 = (idx & 511) << 2;
    const int t  = rp / 320;
    const int q  = rp - t * 320;
    const int g  = q >> 6;
    const int jj = q & 63;
    const int srow = t * 64 + jj;
    const float* src = (g < 3) ? (w_iouh + (size_t)(g * 1024 + srow) * 2048)
                               : (w_fh   + (size_t)((g - 3) * 1024 + srow) * 2048);
    const float4 v = *(const float4*)(src + c4);
    ushort4 o;
    o.x = f2bf_(v.x); o.y = f2bf_(v.y); o.z = f2bf_(v.z); o.w = f2bf_(v.w);
    *(ushort4*)(dst + (size_t)rp * 2048 + c4) = o;
}

// g: [rows,3072] bf16 = [ix|ox|ux]
__global__ void leaf_gates(const unsigned short* __restrict__ g, const float* __restrict__ b,
                           unsigned short* __restrict__ c_out, unsigned short* __restrict__ h_out,
                           int rows)
{
    const int idx = blockIdx.x * blockDim.x + threadIdx.x;
    if (idx >= rows * 256) return;
    const int r = idx >> 8, q = (idx & 255) << 2;
    const unsigned short* gr = g + (size_t)r * 3072;
    const ushort4 ix = *(const ushort4*)(gr + q);
    const ushort4 ox = *(const ushort4*)(gr + 1024 + q);
    const ushort4 ux = *(const ushort4*)(gr + 2048 + q);
    const float* bi = b + 1024 + q;
    const float* bo = b + 2048 + q;
    const float* bu = b + 3072 + q;
    ushort4 co, ho;
    const float c0 = sig_(bf2f_(ix.x) + bi[0]) * tanhf(bf2f_(ux.x) + bu[0]);
    const float c1 = sig_(bf2f_(ix.y) + bi[1]) * tanhf(bf2f_(ux.y) + bu[1]);
    const float c2 = sig_(bf2f_(ix.z) + bi[2]) * tanhf(bf2f_(ux.z) + bu[2]);
    const float c3 = sig_(bf2f_(ix.w) + bi[3]) * tanhf(bf2f_(ux.w) + bu[3]);
    co.x = f2bf_(c0); co.y = f2bf_(c1); co.z = f2bf_(c2); co.w = f2bf_(c3);
    ho.x = f2bf_(sig_(bf2f_(ox.x) + bo[0]) * tanhf(c0));
    ho.y = f2bf_(sig_(bf2f_(ox.y) + bo[1]) * tanhf(c1));
    ho.z = f2bf_(sig_(bf2f_(ox.z) + bo[2]) * tanhf(c2));
    ho.w = f2bf_(sig_(bf2f_(ox.w) + bo[3]) * tanhf(c3));
    *(ushort4*)(c_out + (size_t)r * 1024 + q) = co;
    *(ushort4*)(h_out + (size_t)r * 1024 + q) = ho;
}

__device__ __forceinline__ void acc4_(float* v, ushort4 u) {
    v[0] += bf2f_(u.x); v[1] += bf2f_(u.y); v[2] += bf2f_(u.z); v[3] += bf2f_(u.w);
}

// g: S bf16 partials of [rows,5120] in wcatP column order (16 groups of
// [ih64|oh64|uh64|fl64|fr64]); c_prev bf16 [rows,2048].
__global__ void node_gates(const unsigned short* __restrict__ g, int S, size_t sstride,
                           const float* __restrict__ b,
                           const unsigned short* __restrict__ c_prev,
                           unsigned short* __restrict__ c_out,
                           unsigned short* __restrict__ h_bf,
                           float* __restrict__ h_f32, int rows)
{
    const int idx = blockIdx.x * blockDim.x + threadIdx.x;
    if (idx >= rows * 256) return;
    const int r = idx >> 8, q = (idx & 255) << 2;   // j = q..q+3
    const int t = q >> 6, jj = q & 63;
    float vi[4] = {}, vo[4] = {}, vu[4] = {}, vfl[4] = {}, vfr[4] = {};
    const unsigned short* gr = g + (size_t)r * 5120 + t * 320 + jj;
    for (int s = 0; s < S; ++s, gr += sstride) {
        acc4_(vi,  *(const ushort4*)(gr));
        acc4_(vo,  *(const ushort4*)(gr + 64));
        acc4_(vu,  *(const ushort4*)(gr + 128));
        acc4_(vfl, *(const ushort4*)(gr + 192));
        acc4_(vfr, *(const ushort4*)(gr + 256));
    }
    const float* bi = b + 1024 + q;
    const float* bo = b + 2048 + q;
    const float* bu = b + 3072 + q;
    const float* bff = b + q;
    const ushort4 clu = *(const ushort4*)(c_prev + (size_t)r * 2048 + q);
    const ushort4 cru = *(const ushort4*)(c_prev + (size_t)r * 2048 + 1024 + q);
    const float cl[4] = { bf2f_(clu.x), bf2f_(clu.y), bf2f_(clu.z), bf2f_(clu.w) };
    const float cr[4] = { bf2f_(cru.x), bf2f_(cru.y), bf2f_(cru.z), bf2f_(cru.w) };

    ushort4 co, ho;
    float cv[4], hv[4];
    #pragma unroll
    for (int e = 0; e < 4; ++e) {
        const float c = sig_(vi[e] + bi[e]) * tanhf(vu[e] + bu[e])
                      + sig_(vfl[e] + bff[e]) * cl[e]
                      + sig_(vfr[e] + bff[e]) * cr[e];
        cv[e] = c;
        hv[e] = sig_(vo[e] + bo[e]) * tanhf(c);
    }
    co.x = f2bf_(cv[0]); co.y = f2bf_(cv[1]); co.z = f2bf_(cv[2]); co.w = f2bf_(cv[3]);
    ho.x = f2bf_(hv[0]); ho.y = f2bf_(hv[1]); ho.z = f2bf_(hv[2]); ho.w = f2bf_(hv[3]);
    *(ushort4*)(c_out + (size_t)r * 1024 + q) = co;
    *(ushort4*)(h_bf + (size_t)r * 1024 + q) = ho;
    if (h_f32) {
        float4 hf; hf.x = hv[0]; hf.y = hv[1]; hf.z = hv[2]; hf.w = hv[3];
        *(float4*)(h_f32 + (size_t)r * 1024 + q) = hf;
    }
}

extern "C" void kernel_launch(void* const* d_in, const int* in_sizes, int n_in,
                              void* d_out, int out_size, void* d_ws, size_t ws_size,
                              hipStream_t stream)
{
    const float* inputs  = (const float*)d_in[0];  // [16384,1024]
    const float* w_fioux = (const float*)d_in[1];  // [4096,1024]
    const float* b_fioux = (const float*)d_in[2];  // [4096]
    const float* w_iouh  = (const float*)d_in[3];  // [3072,2048]
    const float* w_fh    = (const float*)d_in[4];  // [2048,2048]
    float* out = (float*)d_out;                    // [32,1024]

    // ---- ws layout, bf16 units (228.6 MB, same as proven round-4 size) ----
    unsigned short* us    = (unsigned short*)d_ws;
    unsigned short* c_a   = us;                          // 16777216
    unsigned short* c_b   = c_a + (size_t)16777216;      //  8388608
    unsigned short* h_a   = c_b + (size_t)8388608;       // 16777216
    unsigned short* h_b   = h_a + (size_t)16777216;      //  8388608
    unsigned short* wfx   = h_b + (size_t)8388608;       //  3145728
    unsigned short* wcatP = wfx + (size_t)3145728;       // 10485760
    unsigned short* gbuf  = wcatP + (size_t)10485760;    // 50331648 (tail only)
    unsigned short* x_bf  = c_a;   // alias: x dead before leaf_gates writes c_a

    // ---- one-time conversions / weight permute ----
    f2bf_vec<<<16384, 256, 0, stream>>>(inputs, x_bf, 4194304);
    f2bf_vec<<<3072, 256, 0, stream>>>(w_fioux + (size_t)1024 * 1024, wfx, 786432);
    build_wcatp<<<10240, 256, 0, stream>>>(w_iouh, w_fh, wcatP, 5120 * 512);

    // ---- leaf level: 16384 rows, K=1024, N=3072 ----
    gemm256<<<dim3(12, 64, 1), 512, 0, stream>>>(x_bf, wfx, gbuf, 16384, 3072, 1024, 1024);
    leaf_gates<<<16384, 256, 0, stream>>>(gbuf, b_fioux, c_a, h_a, 16384);

    // ---- fused internal levels: n = 256, 128, 64 ----
    unsigned short *hp = h_a, *cp = c_a, *hn = h_b, *cn = c_b;
    for (int n = 256; n >= 64; n >>= 1) {
        const int m = 32 * n;
        gemm320f<<<dim3(16, m / 256), 512, 0, stream>>>(hp, wcatP, b_fioux, cp, cn, hn, m);
        unsigned short* t;
        t = hp; hp = hn; hn = t;
        t = cp; cp = cn; cn = t;
    }

    // ---- tail levels: n = 32 .. 1, split-K + node_gates ----
    for (int n = 32; n >= 1; n >>= 1) {
        const int m = 32 * n;
        const int S = (m >= 512) ? 4 : 8;
        const int Klen = 2048 / S;
        gemm256<<<dim3(20, (m + 255) / 256, S), 512, 0, stream>>>(
            hp, wcatP, gbuf, m, 5120, 2048, Klen);
        node_gates<<<m, 256, 0, stream>>>(
            gbuf, S, (size_t)m * 5120, b_fioux, cp, cn, hn,
            (n == 1) ? out : nullptr, m);
        unsigned short* t;
        t = hp; hp = hn; hn = t;
        t = cp; cp = cn; cn = t;
    }
    (void)in_sizes; (void)n_in; (void)out_size; (void)ws_size;
}

// Round 6
// 707.955 us; speedup vs baseline: 13.3575x; 1.0401x over previous
//
#include <hip/hip_runtime.h>
#include <cstdint>
#include <cstddef>

// BinaryTreeLSTM — pipelined bf16 MFMA GEMMs, fused gate epilogue on big levels.
// Round 6: single-barrier phases; ds_reads left to compiler's fine-grained
// lgkmcnt (no forced drain); counted vmcnt ladder at end of phase.
// Race ledger (4-slot circular LDS, lookahead 3):
//   publish slot p+1: end-of-p vmcnt(2L)+barrier (kh p+1 landed; L=loads/phase)
//   WAR slot (p+3)%4=(p-1)%4: phase p-1's reads all consumed by its MFMAs
//     (lgkm-retired) before its end-of-phase barrier; phase p stages after it.
//   epilogue ladder: p=P-3 -> vmcnt(L), p=P-2 -> vmcnt(0), p=P-1 -> no wait.

typedef __attribute__((ext_vector_type(8))) short bf16x8;
typedef __attribute__((ext_vector_type(4))) float f32x4;

__device__ __forceinline__ float sig_(float x) { return 1.0f / (1.0f + __expf(-x)); }

__device__ __forceinline__ unsigned short f2bf_(float x) {
    union { float f; uint32_t u; } v; v.f = x;
    uint32_t r = v.u + 0x7fffu + ((v.u >> 16) & 1u);   // RNE
    return (unsigned short)(r >> 16);
}
__device__ __forceinline__ float bf2f_(unsigned short u) {
    union { uint32_t u; float f; } v; v.u = ((uint32_t)u) << 16; return v.f;
}

#define GL16(g, l) __builtin_amdgcn_global_load_lds( \
    (const __attribute__((address_space(1))) void*)(g), \
    (__attribute__((address_space(3))) void*)(l), 16, 0, 0)

// ---------------------------------------------------------------------------
// gemm256: partial[bz][M,N] bf16 = A[M, kr] @ W[N, kr]^T ; kr = [bz*Klen,+Klen)
// 4 loads/thread/phase -> vmcnt ladder 8/4/0.
// ---------------------------------------------------------------------------
__global__ __launch_bounds__(512, 2)
void gemm256(const unsigned short* __restrict__ A,
             const unsigned short* __restrict__ W,
             unsigned short* __restrict__ C, int M, int N, int lda, int Klen)
{
    __shared__ unsigned short lA[4 * 8192];   // 64 KB
    __shared__ unsigned short lB[4 * 8192];   // 64 KB

    const int gx = gridDim.x, gy = gridDim.y;
    int id = blockIdx.x + gx * (blockIdx.y + gy * blockIdx.z);
    {
        const int nwg = gx * gy * gridDim.z;
        const int q = nwg >> 3, r = nwg & 7, x = id & 7, i = id >> 3;
        id = (x < r ? x * (q + 1) : r * (q + 1) + (x - r) * q) + i;
    }
    const int bz  = id / (gx * gy);
    const int rem = id - bz * gx * gy;
    const int by  = rem / gx;
    const int bx  = rem - by * gx;

    const int tid = threadIdx.x;
    const int ln  = tid & 63;
    const int wv  = tid >> 6;
    const int wrp = wv >> 2;
    const int wcp = wv & 3;
    const int row0 = by * 256;
    const int colb = bx * 256;
    const int kbase = bz * Klen;
    C += (size_t)bz * M * N;

    const int rowS = tid >> 2;
    const int gS   = (tid & 3) ^ ((tid >> 3) & 3);
    const unsigned short* a0 = A + (size_t)min(row0 + rowS,       M - 1) * lda + kbase + gS * 8;
    const unsigned short* a1 = A + (size_t)min(row0 + rowS + 128, M - 1) * lda + kbase + gS * 8;
    const unsigned short* b0 = W + (size_t)(colb + rowS)       * lda + kbase + gS * 8;
    const unsigned short* b1 = W + (size_t)(colb + rowS + 128) * lda + kbase + gS * 8;
    const int ld0 = tid * 8;
    const int ld1 = tid * 8 + 4096;

    int offA[8], offB[4];
    #pragma unroll
    for (int i = 0; i < 8; ++i) {
        const int r = wrp * 128 + i * 16 + (ln & 15);
        offA[i] = r * 32 + ((ln >> 4) ^ ((r >> 1) & 3)) * 8;
    }
    #pragma unroll
    for (int i = 0; i < 4; ++i) {
        const int r = wcp * 64 + i * 16 + (ln & 15);
        offB[i] = r * 32 + ((ln >> 4) ^ ((r >> 1) & 3)) * 8;
    }

    f32x4 acc[8][4] = {};
    const int P = Klen >> 5;   // K=32 phases

#define ISSUE_KH(kh) do { \
    const int _sl = (kh) & 3; \
    const size_t _ko = (size_t)(kh) * 32; \
    GL16(a0 + _ko, lA + _sl * 8192 + ld0); \
    GL16(a1 + _ko, lA + _sl * 8192 + ld1); \
    GL16(b0 + _ko, lB + _sl * 8192 + ld0); \
    GL16(b1 + _ko, lB + _sl * 8192 + ld1); \
} while (0)

    ISSUE_KH(0); ISSUE_KH(1); ISSUE_KH(2);
    asm volatile("s_waitcnt vmcnt(8)" ::: "memory");
    asm volatile("s_barrier" ::: "memory");

    for (int p = 0; p < P; ++p) {
        const unsigned short* pa = lA + (p & 3) * 8192;
        const unsigned short* pb = lB + (p & 3) * 8192;
        bf16x8 bf[4], af[4], ag[4];
        #pragma unroll
        for (int i = 0; i < 4; ++i) bf[i] = *(const bf16x8*)(pb + offB[i]);
        #pragma unroll
        for (int i = 0; i < 4; ++i) af[i] = *(const bf16x8*)(pa + offA[i]);
        #pragma unroll
        for (int i = 0; i < 4; ++i) ag[i] = *(const bf16x8*)(pa + offA[4 + i]);
        if (p <= P - 4) ISSUE_KH(p + 3);
        __builtin_amdgcn_s_setprio(1);
        #pragma unroll
        for (int m = 0; m < 4; ++m)
            #pragma unroll
            for (int n = 0; n < 4; ++n)
                acc[m][n] = __builtin_amdgcn_mfma_f32_16x16x32_bf16(af[m], bf[n], acc[m][n], 0, 0, 0);
        #pragma unroll
        for (int m = 0; m < 4; ++m)
            #pragma unroll
            for (int n = 0; n < 4; ++n)
                acc[4 + m][n] = __builtin_amdgcn_mfma_f32_16x16x32_bf16(ag[m], bf[n], acc[4 + m][n], 0, 0, 0);
        __builtin_amdgcn_s_setprio(0);
        if (p <= P - 4)      asm volatile("s_waitcnt vmcnt(8)" ::: "memory");
        else if (p == P - 3) asm volatile("s_waitcnt vmcnt(4)" ::: "memory");
        else if (p == P - 2) asm volatile("s_waitcnt vmcnt(0)" ::: "memory");
        if (p < P - 1) asm volatile("s_barrier" ::: "memory");
    }
#undef ISSUE_KH

    #pragma unroll
    for (int mi = 0; mi < 8; ++mi) {
        #pragma unroll
        for (int ni = 0; ni < 4; ++ni) {
            const int col = colb + wcp * 64 + ni * 16 + (ln & 15);
            #pragma unroll
            for (int rg = 0; rg < 4; ++rg) {
                const int r = row0 + wrp * 128 + mi * 16 + (ln >> 4) * 4 + rg;
                if (r < M) C[(size_t)r * N + col] = f2bf_(acc[mi][ni][rg]);
            }
        }
    }
}

// ---------------------------------------------------------------------------
// gemm320f: fused internal level. A[M,2048]bf16, Wp[5120,2048]bf16 permuted
// (16 groups of 320 rows = [ih|oh|uh|fl|fr] for 64 consecutive j).
// Waves 0-3 carry 5 loads/phase (vmcnt 10/5/0), waves 4-7 carry 4 (8/4/0).
// ---------------------------------------------------------------------------
__global__ __launch_bounds__(512, 2)
void gemm320f(const unsigned short* __restrict__ A,
              const unsigned short* __restrict__ Wp,
              const float* __restrict__ b,
              const unsigned short* __restrict__ c_prev,
              unsigned short* __restrict__ c_out,
              unsigned short* __restrict__ h_out,
              int M)
{
    __shared__ unsigned short lA[4 * 8192];    // 64 KB
    __shared__ unsigned short lB[4 * 10240];   // 80 KB
    const int lda = 2048;

    const int gx = gridDim.x, gy = gridDim.y;
    int id = blockIdx.x + gx * blockIdx.y;
    {
        const int nwg = gx * gy;
        const int q = nwg >> 3, r = nwg & 7, x = id & 7, i = id >> 3;
        id = (x < r ? x * (q + 1) : r * (q + 1) + (x - r) * q) + i;
    }
    const int by = id / gx;
    const int bx = id - by * gx;

    const int tid = threadIdx.x;
    const int ln  = tid & 63;
    const int wv  = tid >> 6;
    const int wrp = wv >> 2;
    const int wcp = wv & 3;
    const int row0 = by * 256;
    const int colb = bx * 320;
    const bool five = (wv < 4);      // wave-uniform: carries the 5th B load

    const int rowS = tid >> 2;
    const int gS   = (tid & 3) ^ ((tid >> 3) & 3);
    const unsigned short* a0 = A + (size_t)min(row0 + rowS,       M - 1) * lda + gS * 8;
    const unsigned short* a1 = A + (size_t)min(row0 + rowS + 128, M - 1) * lda + gS * 8;
    const unsigned short* w0 = Wp + (size_t)(colb + rowS)       * lda + gS * 8;
    const unsigned short* w1 = Wp + (size_t)(colb + rowS + 128) * lda + gS * 8;
    const unsigned short* w2 = Wp + (size_t)(colb + 256 + ((tid & 255) >> 2)) * lda + gS * 8;
    const int ld0 = tid * 8;
    const int ld1 = tid * 8 + 4096;
    const int ld2 = (tid & 255) * 8 + 8192;

    int offA[8], offB[5];
    #pragma unroll
    for (int i = 0; i < 8; ++i) {
        const int r = wrp * 128 + i * 16 + (ln & 15);
        offA[i] = r * 32 + ((ln >> 4) ^ ((r >> 1) & 3)) * 8;
    }
    #pragma unroll
    for (int g = 0; g < 5; ++g) {
        const int r = g * 64 + wcp * 16 + (ln & 15);
        offB[g] = r * 32 + ((ln >> 4) ^ ((r >> 1) & 3)) * 8;
    }

    f32x4 acc[8][5] = {};
    const int P = 64;   // 2048 / 32

#define ISSUE_F(kh) do { \
    const int _sl = (kh) & 3; \
    const size_t _ko = (size_t)(kh) * 32; \
    GL16(a0 + _ko, lA + _sl * 8192 + ld0); \
    GL16(a1 + _ko, lA + _sl * 8192 + ld1); \
    GL16(w0 + _ko, lB + _sl * 10240 + ld0); \
    GL16(w1 + _ko, lB + _sl * 10240 + ld1); \
    if (five) GL16(w2 + _ko, lB + _sl * 10240 + ld2); \
} while (0)

    ISSUE_F(0); ISSUE_F(1); ISSUE_F(2);
    if (five) asm volatile("s_waitcnt vmcnt(10)" ::: "memory");
    else      asm volatile("s_waitcnt vmcnt(8)"  ::: "memory");
    asm volatile("s_barrier" ::: "memory");

    for (int p = 0; p < P; ++p) {
        const unsigned short* pa = lA + (p & 3) * 8192;
        const unsigned short* pb = lB + (p & 3) * 10240;
        bf16x8 bf[5], af[4], ag[4];
        #pragma unroll
        for (int g = 0; g < 5; ++g) bf[g] = *(const bf16x8*)(pb + offB[g]);
        #pragma unroll
        for (int i = 0; i < 4; ++i) af[i] = *(const bf16x8*)(pa + offA[i]);
        #pragma unroll
        for (int i = 0; i < 4; ++i) ag[i] = *(const bf16x8*)(pa + offA[4 + i]);
        if (p <= P - 4) ISSUE_F(p + 3);
        __builtin_amdgcn_s_setprio(1);
        #pragma unroll
        for (int m = 0; m < 4; ++m)
            #pragma unroll
            for (int g = 0; g < 5; ++g)
                acc[m][g] = __builtin_amdgcn_mfma_f32_16x16x32_bf16(af[m], bf[g], acc[m][g], 0, 0, 0);
        #pragma unroll
        for (int m = 0; m < 4; ++m)
            #pragma unroll
            for (int g = 0; g < 5; ++g)
                acc[4 + m][g] = __builtin_amdgcn_mfma_f32_16x16x32_bf16(ag[m], bf[g], acc[4 + m][g], 0, 0, 0);
        __builtin_amdgcn_s_setprio(0);
        if (p <= P - 4) {
            if (five) asm volatile("s_waitcnt vmcnt(10)" ::: "memory");
            else      asm volatile("s_waitcnt vmcnt(8)"  ::: "memory");
        } else if (p == P - 3) {
            if (five) asm volatile("s_waitcnt vmcnt(5)" ::: "memory");
            else      asm volatile("s_waitcnt vmcnt(4)" ::: "memory");
        } else if (p == P - 2) {
            asm volatile("s_waitcnt vmcnt(0)" ::: "memory");
        }
        if (p < P - 1) asm volatile("s_barrier" ::: "memory");
    }
#undef ISSUE_F

    // ---- fused gate epilogue ----
    const int jg = bx * 64 + wcp * 16 + (ln & 15);   // global j in [0,1024)
    const float bi = b[1024 + jg];
    const float bo = b[2048 + jg];
    const float bu = b[3072 + jg];
    const float bff = b[jg];
    #pragma unroll
    for (int mi = 0; mi < 8; ++mi) {
        #pragma unroll
        for (int rg = 0; rg < 4; ++rg) {
            const int r = row0 + wrp * 128 + mi * 16 + (ln >> 4) * 4 + rg;
            if (r < M) {
                const float cl = bf2f_(c_prev[(size_t)r * 2048 + jg]);
                const float cr = bf2f_(c_prev[(size_t)r * 2048 + 1024 + jg]);
                const float iv = sig_(acc[mi][0][rg] + bi);
                const float ov = sig_(acc[mi][1][rg] + bo);
                const float uv = tanhf(acc[mi][2][rg] + bu);
                const float flv = sig_(acc[mi][3][rg] + bff);
                const float frv = sig_(acc[mi][4][rg] + bff);
                const float c = iv * uv + flv * cl + frv * cr;
                const float h = ov * tanhf(c);
                c_out[(size_t)r * 1024 + jg] = f2bf_(c);
                h_out[(size_t)r * 1024 + jg] = f2bf_(h);
            }
        }
    }
}

// ---------------------------------------------------------------------------
__global__ void f2bf_vec(const float* __restrict__ src, unsigned short* __restrict__ dst, int n4)
{
    const int i = blockIdx.x * blockDim.x + threadIdx.x;
    if (i >= n4) return;
    const float4 v = ((const float4*)src)[i];
    ushort4 o;
    o.x = f2bf_(v.x); o.y = f2bf_(v.y); o.z = f2bf_(v.z); o.w = f2bf_(v.w);
    ((ushort4*)dst)[i] = o;
}

// wcatP[rp, :] for rp = t*320 + g*64 + jj  <-  gate-g weight row (t*64+jj)
__global__ void build_wcatp(const float* __restrict__ w_iouh, const float* __restrict__ w_fh,
                            unsigned short* __restrict__ dst, int total4)
{
    const int idx = blockIdx.x * blockDim.x + threadIdx.x;
    if (idx >= total4) return;
    const int rp = idx >> 9;            // 0..5119
    const int c4 = (idx & 511) << 2;
    const int t  = rp / 320;
    const int q  = rp - t * 320;
    const int g  = q >> 6;
    const int jj = q & 63;
    const int srow = t * 64 + jj;
    const float* src = (g < 3) ? (w_iouh + (size_t)(g * 1024 + srow) * 2048)
                               : (w_fh   + (size_t)((g - 3) * 1024 + srow) * 2048);
    const float4 v = *(const float4*)(src + c4);
    ushort4 o;
    o.x = f2bf_(v.x); o.y = f2bf_(v.y); o.z = f2bf_(v.z); o.w = f2bf_(v.w);
    *(ushort4*)(dst + (size_t)rp * 2048 + c4) = o;
}

// g: [rows,3072] bf16 = [ix|ox|ux]
__global__ void leaf_gates(const unsigned short* __restrict__ g, const float* __restrict__ b,
                           unsigned short* __restrict__ c_out, unsigned short* __restrict__ h_out,
                           int rows)
{
    const int idx = blockIdx.x * blockDim.x + threadIdx.x;
    if (idx >= rows * 256) return;
    const int r = idx >> 8, q = (idx & 255) << 2;
    const unsigned short* gr = g + (size_t)r * 3072;
    const ushort4 ix = *(const ushort4*)(gr + q);
    const ushort4 ox = *(const ushort4*)(gr + 1024 + q);
    const ushort4 ux = *(const ushort4*)(gr + 2048 + q);
    const float* bi = b + 1024 + q;
    const float* bo = b + 2048 + q;
    const float* bu = b + 3072 + q;
    ushort4 co, ho;
    const float c0 = sig_(bf2f_(ix.x) + bi[0]) * tanhf(bf2f_(ux.x) + bu[0]);
    const float c1 = sig_(bf2f_(ix.y) + bi[1]) * tanhf(bf2f_(ux.y) + bu[1]);
    const float c2 = sig_(bf2f_(ix.z) + bi[2]) * tanhf(bf2f_(ux.z) + bu[2]);
    const float c3 = sig_(bf2f_(ix.w) + bi[3]) * tanhf(bf2f_(ux.w) + bu[3]);
    co.x = f2bf_(c0); co.y = f2bf_(c1); co.z = f2bf_(c2); co.w = f2bf_(c3);
    ho.x = f2bf_(sig_(bf2f_(ox.x) + bo[0]) * tanhf(c0));
    ho.y = f2bf_(sig_(bf2f_(ox.y) + bo[1]) * tanhf(c1));
    ho.z = f2bf_(sig_(bf2f_(ox.z) + bo[2]) * tanhf(c2));
    ho.w = f2bf_(sig_(bf2f_(ox.w) + bo[3]) * tanhf(c3));
    *(ushort4*)(c_out + (size_t)r * 1024 + q) = co;
    *(ushort4*)(h_out + (size_t)r * 1024 + q) = ho;
}

__device__ __forceinline__ void acc4_(float* v, ushort4 u) {
    v[0] += bf2f_(u.x); v[1] += bf2f_(u.y); v[2] += bf2f_(u.z); v[3] += bf2f_(u.w);
}

// g: S bf16 partials of [rows,5120] in wcatP column order (16 groups of
// [ih64|oh64|uh64|fl64|fr64]); c_prev bf16 [rows,2048].
__global__ void node_gates(const unsigned short* __restrict__ g, int S, size_t sstride,
                           const float* __restrict__ b,
                           const unsigned short* __restrict__ c_prev,
                           unsigned short* __restrict__ c_out,
                           unsigned short* __restrict__ h_bf,
                           float* __restrict__ h_f32, int rows)
{
    const int idx = blockIdx.x * blockDim.x + threadIdx.x;
    if (idx >= rows * 256) return;
    const int r = idx >> 8, q = (idx & 255) << 2;   // j = q..q+3
    const int t = q >> 6, jj = q & 63;
    float vi[4] = {}, vo[4] = {}, vu[4] = {}, vfl[4] = {}, vfr[4] = {};
    const unsigned short* gr = g + (size_t)r * 5120 + t * 320 + jj;
    for (int s = 0; s < S; ++s, gr += sstride) {
        acc4_(vi,  *(const ushort4*)(gr));
        acc4_(vo,  *(const ushort4*)(gr + 64));
        acc4_(vu,  *(const ushort4*)(gr + 128));
        acc4_(vfl, *(const ushort4*)(gr + 192));
        acc4_(vfr, *(const ushort4*)(gr + 256));
    }
    const float* bi = b + 1024 + q;
    const float* bo = b + 2048 + q;
    const float* bu = b + 3072 + q;
    const float* bff = b + q;
    const ushort4 clu = *(const ushort4*)(c_prev + (size_t)r * 2048 + q);
    const ushort4 cru = *(const ushort4*)(c_prev + (size_t)r * 2048 + 1024 + q);
    const float cl[4] = { bf2f_(clu.x), bf2f_(clu.y), bf2f_(clu.z), bf2f_(clu.w) };
    const float cr[4] = { bf2f_(cru.x), bf2f_(cru.y), bf2f_(cru.z), bf2f_(cru.w) };

    ushort4 co, ho;
    float cv[4], hv[4];
    #pragma unroll
    for (int e = 0; e < 4; ++e) {
        const float c = sig_(vi[e] + bi[e]) * tanhf(vu[e] + bu[e])
                      + sig_(vfl[e] + bff[e]) * cl[e]
                      + sig_(vfr[e] + bff[e]) * cr[e];
        cv[e] = c;
        hv[e] = sig_(vo[e] + bo[e]) * tanhf(c);
    }
    co.x = f2bf_(cv[0]); co.y = f2bf_(cv[1]); co.z = f2bf_(cv[2]); co.w = f2bf_(cv[3]);
    ho.x = f2bf_(hv[0]); ho.y = f2bf_(hv[1]); ho.z = f2bf_(hv[2]); ho.w = f2bf_(hv[3]);
    *(ushort4*)(c_out + (size_t)r * 1024 + q) = co;
    *(ushort4*)(h_bf + (size_t)r * 1024 + q) = ho;
    if (h_f32) {
        float4 hf; hf.x = hv[0]; hf.y = hv[1]; hf.z = hv[2]; hf.w = hv[3];
        *(float4*)(h_f32 + (size_t)r * 1024 + q) = hf;
    }
}

extern "C" void kernel_launch(void* const* d_in, const int* in_sizes, int n_in,
                              void* d_out, int out_size, void* d_ws, size_t ws_size,
                              hipStream_t stream)
{
    const float* inputs  = (const float*)d_in[0];  // [16384,1024]
    const float* w_fioux = (const float*)d_in[1];  // [4096,1024]
    const float* b_fioux = (const float*)d_in[2];  // [4096]
    const float* w_iouh  = (const float*)d_in[3];  // [3072,2048]
    const float* w_fh    = (const float*)d_in[4];  // [2048,2048]
    float* out = (float*)d_out;                    // [32,1024]

    // ---- ws layout, bf16 units (228.6 MB, proven size) ----
    unsigned short* us    = (unsigned short*)d_ws;
    unsigned short* c_a   = us;                          // 16777216
    unsigned short* c_b   = c_a + (size_t)16777216;      //  8388608
    unsigned short* h_a   = c_b + (size_t)8388608;       // 16777216
    unsigned short* h_b   = h_a + (size_t)16777216;      //  8388608
    unsigned short* wfx   = h_b + (size_t)8388608;       //  3145728
    unsigned short* wcatP = wfx + (size_t)3145728;       // 10485760
    unsigned short* gbuf  = wcatP + (size_t)10485760;    // 50331648 (tail only)
    unsigned short* x_bf  = c_a;   // alias: x dead before leaf_gates writes c_a

    // ---- one-time conversions / weight permute ----
    f2bf_vec<<<16384, 256, 0, stream>>>(inputs, x_bf, 4194304);
    f2bf_vec<<<3072, 256, 0, stream>>>(w_fioux + (size_t)1024 * 1024, wfx, 786432);
    build_wcatp<<<10240, 256, 0, stream>>>(w_iouh, w_fh, wcatP, 5120 * 512);

    // ---- leaf level: 16384 rows, K=1024, N=3072 ----
    gemm256<<<dim3(12, 64, 1), 512, 0, stream>>>(x_bf, wfx, gbuf, 16384, 3072, 1024, 1024);
    leaf_gates<<<16384, 256, 0, stream>>>(gbuf, b_fioux, c_a, h_a, 16384);

    // ---- fused internal levels: n = 256, 128, 64 ----
    unsigned short *hp = h_a, *cp = c_a, *hn = h_b, *cn = c_b;
    for (int n = 256; n >= 64; n >>= 1) {
        const int m = 32 * n;
        gemm320f<<<dim3(16, m / 256), 512, 0, stream>>>(hp, wcatP, b_fioux, cp, cn, hn, m);
        unsigned short* t;
        t = hp; hp = hn; hn = t;
        t = cp; cp = cn; cn = t;
    }

    // ---- tail levels: n = 32 .. 1, split-K + node_gates ----
    for (int n = 32; n >= 1; n >>= 1) {
        const int m = 32 * n;
        const int S = (m >= 512) ? 4 : 8;
        const int Klen = 2048 / S;
        gemm256<<<dim3(20, (m + 255) / 256, S), 512, 0, stream>>>(
            hp, wcatP, gbuf, m, 5120, 2048, Klen);
        node_gates<<<m, 256, 0, stream>>>(
            gbuf, S, (size_t)m * 5120, b_fioux, cp, cn, hn,
            (n == 1) ? out : nullptr, m);
        unsigned short* t;
        t = hp; hp = hn; hn = t;
        t = cp; cp = cn; cn = t;
    }
    (void)in_sizes; (void)n_in; (void)out_size; (void)ws_size;
}